// Round 4
// baseline (730.718 us; speedup 1.0000x reference)
//
#include <hip/hip_runtime.h>

typedef __bf16 bf16;
typedef __attribute__((ext_vector_type(8))) __bf16 bf16x8;
typedef __attribute__((ext_vector_type(4))) float f32x4;

#define MPTS 40960
#define NC 15
#define GX 1280
#define GY 948
#define HH 640
#define WW 474
#define CROPN 320
#define JW 6

#define K1 960    // ky padded 948->960, real input
#define N1G 384   // 161 freqs x {re,im} = 322, padded to 384
#define K2 2560   // [tr(1280 kx) | ti(1280)]
#define N2 384    // 320 r padded to 384

#define NTX 40    // x tiles (1280/32)
#define NTY 30    // y tiles (covers [0,960), cells only [0,948))
#define NTILE (NTX*NTY)   // 1200
#define MAXENT (MPTS*4)

// ---------- modified Bessel I0 (A&S 9.8.1 / 9.8.2) ----------
__device__ __forceinline__ float i0f_dev(float x){
  if (x < 3.75f){
    float t = x*(1.0f/3.75f); t *= t;
    return 1.0f + t*(3.5156229f + t*(3.0899424f + t*(1.2067492f +
                 t*(0.2659732f + t*(0.0360768f + t*0.0045813f)))));
  } else {
    float t = 3.75f/x;
    float p = 0.39894228f + t*(0.01328592f + t*(0.00225319f + t*(-0.00157565f +
              t*(0.00916281f + t*(-0.02057706f + t*(0.02635537f +
              t*(-0.01647633f + t*0.00392377f)))))));
    return __expf(x)*rsqrtf(x)*p;
  }
}

// ---------- per-sample KB weights & 1D indices ----------
__device__ __forceinline__ void kb_compute(const float* __restrict__ ktraj, int m,
                                           float* wx, float* wy, int* ixv, int* iyv){
  const float PI2 = 6.28318530717958647692f;
  float tmx = ktraj[m]        * ((float)GX/PI2);
  float tmy = ktraj[MPTS + m] * ((float)GY/PI2);
  float bx = floorf(tmx - 3.0f), by = floorf(tmy - 3.0f);
  #pragma unroll
  for (int j=0;j<JW;++j){
    float fx = bx + (float)(j+1);
    float u  = tmx - fx;
    float ax = 1.0f - u*u*(1.0f/9.0f);
    float w  = 0.0f;
    if (ax > 0.0f) w = i0f_dev(14.04f*sqrtf(fmaxf(ax,1e-12f)));
    wx[j] = w*(1.0f/6.0f);
    int ii = (int)fx; ii %= GX; if (ii<0) ii += GX; ixv[j] = ii;

    float fy = by + (float)(j+1);
    float v  = tmy - fy;
    float ay = 1.0f - v*v*(1.0f/9.0f);
    float wv = 0.0f;
    if (ay > 0.0f) wv = i0f_dev(14.04f*sqrtf(fmaxf(ay,1e-12f)));
    wy[j] = wv*(1.0f/6.0f);
    int jj = (int)fy; jj %= GY; if (jj<0) jj += GY; iyv[j] = jj;
  }
}

// ---------- sample -> tile footprint ----------
__device__ __forceinline__ void tile_span(const float* __restrict__ ktraj, int m,
                                          int& tx0, int& tx1, int& ty0, int& ty1){
  const float PI2 = 6.28318530717958647692f;
  float tmx = ktraj[m]        * ((float)GX/PI2);
  float tmy = ktraj[MPTS + m] * ((float)GY/PI2);
  int bx = (int)floorf(tmx - 3.0f), by = (int)floorf(tmy - 3.0f);
  int ix0 = ((bx + 1) % GX + GX) % GX;
  int iy0 = ((by + 1) % GY + GY) % GY;
  tx0 = ix0 >> 5;            tx1 = ((ix0 + 5) % GX) >> 5;
  ty0 = iy0 >> 5;            ty1 = ((iy0 + 5) % GY) >> 5;
}

// ---------- ydc[m][c][2] = kspace * dcomp ----------
__global__ void make_ydc(const float* __restrict__ kr, const float* __restrict__ ki,
                         const float* __restrict__ dc, float* __restrict__ ydc){
  int m = blockIdx.x*256 + threadIdx.x;
  if (m >= MPTS) return;
  float d = dc[m];
  #pragma unroll
  for (int c=0;c<NC;++c){
    ydc[((size_t)m*NC + c)*2    ] = kr[(size_t)c*MPTS + m]*d;
    ydc[((size_t)m*NC + c)*2 + 1] = ki[(size_t)c*MPTS + m]*d;
  }
}

// ---------- bin build ----------
__global__ void bin_hist(const float* __restrict__ ktraj, int* __restrict__ bhist){
  int m = blockIdx.x*256 + threadIdx.x;
  if (m >= MPTS) return;
  int tx0,tx1,ty0,ty1; tile_span(ktraj,m,tx0,tx1,ty0,ty1);
  atomicAdd(&bhist[tx0*NTY+ty0],1);
  if (tx1!=tx0) atomicAdd(&bhist[tx1*NTY+ty0],1);
  if (ty1!=ty0){
    atomicAdd(&bhist[tx0*NTY+ty1],1);
    if (tx1!=tx0) atomicAdd(&bhist[tx1*NTY+ty1],1);
  }
}

__global__ __launch_bounds__(256) void bin_scan(const int* __restrict__ bhist,
                                                int* __restrict__ bstart,
                                                int* __restrict__ bcur){
  __shared__ int ps[256];
  int t = threadIdx.x;
  int v[5]; int s = 0;
  #pragma unroll
  for (int j=0;j<5;++j){ int i = t*5+j; v[j] = (i<NTILE)?bhist[i]:0; s += v[j]; }
  ps[t] = s; __syncthreads();
  for (int off=1; off<256; off<<=1){
    int x = (t>=off) ? ps[t-off] : 0;
    __syncthreads();
    ps[t] += x;
    __syncthreads();
  }
  int run = (t==0) ? 0 : ps[t-1];
  #pragma unroll
  for (int j=0;j<5;++j){
    int i = t*5+j;
    if (i<NTILE){ bstart[i]=run; bcur[i]=run; }
    run += v[j];
  }
}

__global__ void bin_fill(const float* __restrict__ ktraj, int* __restrict__ bcur,
                         int* __restrict__ bent){
  int m = blockIdx.x*256 + threadIdx.x;
  if (m >= MPTS) return;
  int tx0,tx1,ty0,ty1; tile_span(ktraj,m,tx0,tx1,ty0,ty1);
  int p = atomicAdd(&bcur[tx0*NTY+ty0],1); bent[p] = m;
  if (tx1!=tx0){ p = atomicAdd(&bcur[tx1*NTY+ty0],1); bent[p] = m; }
  if (ty1!=ty0){
    p = atomicAdd(&bcur[tx0*NTY+ty1],1); bent[p] = m;
    if (tx1!=tx0){ p = atomicAdd(&bcur[tx1*NTY+ty1],1); bent[p] = m; }
  }
}

// ---------- tile scatter: LDS-accumulate one 32x32 grid tile for BC coils,
// write bf16 A1 rows [(cl*1280+kx)*2+ri][K1=960] directly ----------
template<int BC>
__global__ __launch_bounds__(256) void tile_scatter(const float* __restrict__ ktraj,
                                                    const float* __restrict__ ydc,
                                                    const int* __restrict__ bstart,
                                                    const int* __restrict__ bend,
                                                    const int* __restrict__ bent,
                                                    bf16* __restrict__ A1, int c0){
  int tile = blockIdx.x;
  int tx = tile / NTY, ty = tile - tx*NTY;
  int x0 = tx*32, y0 = ty*32;
  __shared__ float lr[BC][32][33];
  __shared__ float li[BC][32][33];
  int t = threadIdx.x;
  float* lrf = &lr[0][0][0];
  float* lif = &li[0][0][0];
  for (int i=t; i<BC*32*33; i+=256){ lrf[i]=0.f; lif[i]=0.f; }
  __syncthreads();

  int beg = bstart[tile], end = bend[tile];
  for (int e = beg + t; e < end; e += 256){
    int m = bent[e];
    float wx[JW], wy[JW]; int ixv[JW], iyv[JW];
    kb_compute(ktraj, m, wx, wy, ixv, iyv);
    float yr[BC], yi[BC];
    const float* yp = ydc + ((size_t)m*NC + c0)*2;
    #pragma unroll
    for (int c=0;c<BC;++c){ yr[c]=yp[2*c]; yi[c]=yp[2*c+1]; }
    #pragma unroll
    for (int a=0;a<JW;++a){
      int lx = ixv[a] - x0;
      if ((unsigned)lx >= 32u) continue;
      #pragma unroll
      for (int b=0;b<JW;++b){
        int ly = iyv[b] - y0;
        if ((unsigned)ly >= 32u) continue;
        float w = wx[a]*wy[b];
        #pragma unroll
        for (int c=0;c<BC;++c){
          atomicAdd(&lr[c][lx][ly], w*yr[c]);
          atomicAdd(&li[c][lx][ly], w*yi[c]);
        }
      }
    }
  }
  __syncthreads();

  // write-out (ky in [y0, y0+32) covers the 948..959 zero padding on last tile)
  for (int i=t; i<BC*32*32; i+=256){
    int c  = i >> 10;
    int r  = (i >> 5) & 31;
    int ly = i & 31;
    int kx = x0 + r, ky = y0 + ly;
    size_t base = ((size_t)(c*GX + kx)*2) * K1;
    A1[base + ky]      = (bf16)lr[c][r][ly];
    A1[base + K1 + ky] = (bf16)li[c][r][ly];
  }
}

// ---------- twiddle gen: B1 [N1G][K1]: rows 2n+p (n<=160), cols ky ----------
__global__ void gen_B1(bf16* __restrict__ B1){
  int i = blockIdx.x*256 + threadIdx.x;
  if (i >= N1G*K1) return;
  int nr = i / K1, k = i - nr*K1;
  int n = nr >> 1, p = nr & 1;
  float v = 0.f;
  if (n <= 160 && k < GY){
    int rem = (k * n) % GY;
    float ang = 6.28318530717958647692f * (float)rem / (float)GY;
    float s, c; sincosf(ang, &s, &c);
    v = p ? s : c;
  }
  B1[i] = (bf16)v;
}

// ---------- twiddle gen: W2t [N2][K2] ----------
__global__ void gen_W2t(bf16* __restrict__ W2t){
  int i = blockIdx.x*256 + threadIdx.x;
  if (i >= N2*K2) return;
  int n = i / K2, k = i - n*K2;
  float v = 0.f;
  if (n < CROPN){
    int part = k / 1280, kx = k - part*1280;
    int nx = (n < 160) ? (1120 + n) : (n - 160);
    int rem = (kx * nx) % GX;
    float ang = 6.28318530717958647692f * (float)rem / (float)GX;
    float s, c; sincosf(ang, &s, &c);
    v = part ? s : c;
  }
  W2t[i] = (bf16)v;
}

// ---------- pack C1 (F_gr, F_gi) -> A2 bf16 [bc*640][K2], Hermitian reconstruct ----------
__global__ void pack_A2(const float* __restrict__ C1, bf16* __restrict__ A2, int total){
  int i = blockIdx.x*256 + threadIdx.x;
  if (i >= total) return;
  int kg  = i % (K2/8);
  int mr2 = i / (K2/8);
  int cl = mr2 / 640;
  int nn = mr2 - cl*640;
  int q = nn >> 1, ri = nn & 1;
  int k0 = kg*8;
  int part = k0 / 1280, kx0 = k0 - part*1280;
  int nyv = q - 160;
  int n = (nyv >= 0) ? nyv : -nyv;
  bf16x8 ov;
  #pragma unroll
  for (int j=0;j<8;++j){
    int kx = kx0 + j;
    const float* r0 = C1 + ((size_t)(cl*GX + kx)*2) * N1G;
    const float* r1 = r0 + N1G;
    float R0 = r0[2*n], I0 = r0[2*n+1];
    float R1 = r1[2*n], I1 = r1[2*n+1];
    float tre, tim;
    if (nyv >= 0){ tre = R0 - I1; tim = I0 + R1; }
    else         { tre = R0 + I1; tim = R1 - I0; }
    float v = (ri == 0) ? (part == 0 ? tre : -tim)
                        : (part == 0 ? tim :  tre);
    ov[j] = (bf16)v;
  }
  *(bf16x8*)(A2 + (size_t)mr2*K2 + k0) = ov;
}

// ---------- bf16 GEMM: C[m][n] = sum_k A[m][k]*B[n][k] ----------
#define BM 128
#define BN 128
#define BK 32
#define LDT 40

__global__ __launch_bounds__(256) void gemm_bt(const bf16* __restrict__ A,
                                               const bf16* __restrict__ B,
                                               float* __restrict__ C,
                                               int K, int ldc){
  __shared__ bf16 As[BM*LDT];
  __shared__ bf16 Bs[BM*LDT];
  int t = threadIdx.x;
  int lane = t & 63;
  int wave = t >> 6;
  int wm = wave >> 1, wn = wave & 1;
  size_t tileM = (size_t)blockIdx.x * BM;
  size_t tileN = (size_t)blockIdx.y * BN;

  const bf16* Ab = A + tileM * K;
  const bf16* Bb = B + tileN * K;

  f32x4 zero = {0.f, 0.f, 0.f, 0.f};
  f32x4 acc[4][4];
  #pragma unroll
  for (int m=0;m<4;++m)
    #pragma unroll
    for (int n=0;n<4;++n) acc[m][n] = zero;

  int r0 = t >> 2;
  int kc = (t & 3) * 8;
  size_t aoff = (size_t)r0 * K + kc;

  bf16x8 a0 = *(const bf16x8*)(Ab + aoff);
  bf16x8 a1 = *(const bf16x8*)(Ab + aoff + (size_t)64*K);
  bf16x8 b0 = *(const bf16x8*)(Bb + aoff);
  bf16x8 b1 = *(const bf16x8*)(Bb + aoff + (size_t)64*K);

  int lr = lane & 15, lk = (lane >> 4) * 8;

  for (int kt = 0; kt < K; kt += BK){
    __syncthreads();
    *(bf16x8*)(As + r0*LDT + kc)      = a0;
    *(bf16x8*)(As + (r0+64)*LDT + kc) = a1;
    *(bf16x8*)(Bs + r0*LDT + kc)      = b0;
    *(bf16x8*)(Bs + (r0+64)*LDT + kc) = b1;
    __syncthreads();

    bool more = (kt + BK) < K;
    if (more){
      size_t o = aoff + kt + BK;
      a0 = *(const bf16x8*)(Ab + o);
      a1 = *(const bf16x8*)(Ab + o + (size_t)64*K);
      b0 = *(const bf16x8*)(Bb + o);
      b1 = *(const bf16x8*)(Bb + o + (size_t)64*K);
    }

    bf16x8 af[4], bg[4];
    #pragma unroll
    for (int m=0;m<4;++m)
      af[m] = *(const bf16x8*)(As + (wm*64 + m*16 + lr)*LDT + lk);
    #pragma unroll
    for (int n=0;n<4;++n)
      bg[n] = *(const bf16x8*)(Bs + (wn*64 + n*16 + lr)*LDT + lk);
    #pragma unroll
    for (int m=0;m<4;++m)
      #pragma unroll
      for (int n=0;n<4;++n)
        acc[m][n] = __builtin_amdgcn_mfma_f32_16x16x32_bf16(af[m], bg[n], acc[m][n], 0, 0, 0);
  }

  int lrow = (lane >> 4) * 4;
  #pragma unroll
  for (int m=0;m<4;++m)
    #pragma unroll
    for (int n=0;n<4;++n){
      size_t row = tileM + wm*64 + m*16 + lrow;
      size_t col = tileN + wn*64 + n*16 + lr;
      #pragma unroll
      for (int r=0;r<4;++r)
        C[(row + r)*(size_t)ldc + col] = acc[m][n][r];
    }
}

// ---------- coil combine into accum ----------
__global__ void combine(const float* __restrict__ C2,
                        const float* __restrict__ smr, const float* __restrict__ smi,
                        float* __restrict__ accum, int c0, int bc){
  int i = blockIdx.x*256 + threadIdx.x;
  if (i >= CROPN*CROPN) return;
  int r = i / CROPN, q = i - r*CROPN;
  float ar = 0.f, ai = 0.f;
  for (int cl=0; cl<bc; ++cl){
    float re = C2[((size_t)cl*640 + 2*q    )*N2 + r];
    float im = C2[((size_t)cl*640 + 2*q + 1)*N2 + r];
    size_t sidx = ((size_t)(c0+cl)*HH + (160+r))*WW + (77+q);
    float sr = smr[sidx], si = smi[sidx];
    ar += sr*re + si*im;
    ai += sr*im - si*re;
  }
  accum[2*i] += ar; accum[2*i+1] += ai;
}

// ---------- deapodization + magnitude ----------
__device__ __forceinline__ float deapod_f(float n, float G){
  float x = 3.14159265358979323846f * 6.0f * n / G;
  float z = 197.1216f - x*x;
  float sz = sqrtf(fabsf(z) + 1e-12f);
  float K;
  if (z > 0.0f){
    float e = __expf(sz);
    K = (e - 1.0f/e)*0.5f/sz;
  } else {
    K = __sinf(sz)/sz;
  }
  return 1.0f/K;
}

__global__ void final_mag(const float* __restrict__ accum, float* __restrict__ out){
  int i = blockIdx.x*256 + threadIdx.x;
  if (i >= CROPN*CROPN) return;
  int r  = i / CROPN;
  int cc = i - r*CROPN;
  float dx = deapod_f((float)(r  - 160), (float)GX);
  float dy = deapod_f((float)(cc - 160), (float)GY);
  float re = accum[2*i], im = accum[2*i+1];
  out[i] = sqrtf(re*re + im*im) * dx * dy;
}

extern "C" void kernel_launch(void* const* d_in, const int* in_sizes, int n_in,
                              void* d_out, int out_size, void* d_ws, size_t ws_size,
                              hipStream_t stream){
  const float* kr    = (const float*)d_in[0];
  const float* ki    = (const float*)d_in[1];
  const float* ktraj = (const float*)d_in[2];
  const float* dc    = (const float*)d_in[3];
  const float* smr   = (const float*)d_in[4];
  const float* smi   = (const float*)d_in[5];
  float* out = (float*)d_out;

  // ---- workspace carve (bytes) ----
  const size_t acc_b   = (size_t)CROPN*CROPN*2*4;    //   819,200
  const size_t B1_b    = (size_t)N1G*K1*2;           //   737,280
  const size_t W2t_b   = (size_t)N2*K2*2;            // 1,966,080
  const size_t ydc_b   = (size_t)MPTS*NC*2*4;        // 4,915,200
  const size_t bh_b    = 8192;
  const size_t bent_b  = (size_t)MAXENT*4;           //   655,360
  const size_t fixed_b = acc_b+B1_b+W2t_b+ydc_b+3*bh_b+bent_b;   // ~9.1 MB

  const size_t A1_pc   = (size_t)GX*2*K1*2;          // 4,915,200 (A2 aliases A1)
  const size_t C1_pc   = (size_t)GX*2*N1G*4;         // 3,932,160
  const size_t C2_pc   = (size_t)640*N2*4;           //   983,040
  const size_t percoil = A1_pc + C1_pc + C2_pc;      // 9,830,400

  int bc = 1;
  if (ws_size > fixed_b + percoil){
    size_t b = (ws_size - fixed_b) / percoil;
    bc = (int)(b > 8 ? 8 : b);
    if (bc < 1) bc = 1;
  }

  char* p = (char*)d_ws;
  float* accum  = (float*)p; p += acc_b;
  bf16*  B1     = (bf16*)p;  p += B1_b;
  bf16*  W2t    = (bf16*)p;  p += W2t_b;
  float* ydc    = (float*)p; p += ydc_b;
  int*   bhist  = (int*)p;   p += bh_b;
  int*   bstart = (int*)p;   p += bh_b;
  int*   bcur   = (int*)p;   p += bh_b;
  int*   bent   = (int*)p;   p += bent_b;
  bf16*  A1     = (bf16*)p;
  bf16*  A2     = (bf16*)p;  p += (size_t)bc*A1_pc;   // A2 aliases A1 (dead after GEMM1)
  float* C1     = (float*)p; p += (size_t)bc*C1_pc;
  float* C2     = (float*)p; p += (size_t)bc*C2_pc;

  // ---- one-time builds ----
  make_ydc<<<(MPTS+255)/256, 256, 0, stream>>>(kr, ki, dc, ydc);
  hipMemsetAsync(bhist, 0, NTILE*4, stream);
  bin_hist<<<(MPTS+255)/256, 256, 0, stream>>>(ktraj, bhist);
  bin_scan<<<1, 256, 0, stream>>>(bhist, bstart, bcur);
  bin_fill<<<(MPTS+255)/256, 256, 0, stream>>>(ktraj, bcur, bent);
  gen_B1<<<(N1G*K1+255)/256, 256, 0, stream>>>(B1);
  gen_W2t<<<(N2*K2+255)/256, 256, 0, stream>>>(W2t);
  hipMemsetAsync(accum, 0, acc_b, stream);

  // ---- per coil-batch pipeline ----
  for (int c0 = 0; c0 < NC; c0 += bc){
    int nb = NC - c0; if (nb > bc) nb = bc;

    switch (nb){
      case 1: tile_scatter<1><<<NTILE,256,0,stream>>>(ktraj,ydc,bstart,bcur,bent,A1,c0); break;
      case 2: tile_scatter<2><<<NTILE,256,0,stream>>>(ktraj,ydc,bstart,bcur,bent,A1,c0); break;
      case 3: tile_scatter<3><<<NTILE,256,0,stream>>>(ktraj,ydc,bstart,bcur,bent,A1,c0); break;
      case 4: tile_scatter<4><<<NTILE,256,0,stream>>>(ktraj,ydc,bstart,bcur,bent,A1,c0); break;
      case 5: tile_scatter<5><<<NTILE,256,0,stream>>>(ktraj,ydc,bstart,bcur,bent,A1,c0); break;
      case 6: tile_scatter<6><<<NTILE,256,0,stream>>>(ktraj,ydc,bstart,bcur,bent,A1,c0); break;
      case 7: tile_scatter<7><<<NTILE,256,0,stream>>>(ktraj,ydc,bstart,bcur,bent,A1,c0); break;
      default: tile_scatter<8><<<NTILE,256,0,stream>>>(ktraj,ydc,bstart,bcur,bent,A1,c0); break;
    }

    // GEMM1: [nb*2560][960] x [384][960]^T -> C1 [nb*2560][384]
    gemm_bt<<<dim3(nb*(GX*2/BM), N1G/BN), 256, 0, stream>>>(A1, B1, C1, K1, N1G);

    int tot2 = nb*640*(K2/8);
    pack_A2<<<(tot2+255)/256, 256, 0, stream>>>(C1, A2, tot2);

    // GEMM2: [nb*640][2560] x [384][2560]^T -> C2 [nb*640][384]
    gemm_bt<<<dim3(nb*(640/BM), N2/BN), 256, 0, stream>>>(A2, W2t, C2, K2, N2);

    combine<<<(CROPN*CROPN+255)/256, 256, 0, stream>>>(C2, smr, smi, accum, c0, nb);
  }
  final_mag<<<(CROPN*CROPN+255)/256, 256, 0, stream>>>(accum, out);
}

// Round 5
// 700.250 us; speedup vs baseline: 1.0435x; 1.0435x over previous
//
#include <hip/hip_runtime.h>

typedef __bf16 bf16;
typedef __attribute__((ext_vector_type(8))) __bf16 bf16x8;
typedef __attribute__((ext_vector_type(4))) float f32x4;

#define MPTS 40960
#define NC 15
#define GX 1280
#define GY 948
#define HH 640
#define WW 474
#define CROPN 320
#define JW 6

#define K1 960    // ky padded 948->960, real input
#define N1G 384   // 161 freqs x {re,im} = 322, padded to 384
#define K2 2560   // [tr(1280 kx) | ti(1280)]
#define N2 384    // 320 r padded to 384

#define NTX 40    // x tiles (1280/32)
#define NTY 30    // y tiles (covers [0,960), cells only [0,948))
#define NTILE (NTX*NTY)   // 1200
#define MAXENT (MPTS*4)

// ---------- modified Bessel I0 (A&S 9.8.1 / 9.8.2) ----------
__device__ __forceinline__ float i0f_dev(float x){
  if (x < 3.75f){
    float t = x*(1.0f/3.75f); t *= t;
    return 1.0f + t*(3.5156229f + t*(3.0899424f + t*(1.2067492f +
                 t*(0.2659732f + t*(0.0360768f + t*0.0045813f)))));
  } else {
    float t = 3.75f/x;
    float p = 0.39894228f + t*(0.01328592f + t*(0.00225319f + t*(-0.00157565f +
              t*(0.00916281f + t*(-0.02057706f + t*(0.02635537f +
              t*(-0.01647633f + t*0.00392377f)))))));
    return __expf(x)*rsqrtf(x)*p;
  }
}

// ---------- 1D KB weight + wrapped index for one tap j ----------
__device__ __forceinline__ void kb_tap(float tm, float base, int j, int G,
                                       float& w, int& idx){
  float f = base + (float)(j+1);
  float u = tm - f;
  float a = 1.0f - u*u*(1.0f/9.0f);
  w = 0.0f;
  if (a > 0.0f) w = i0f_dev(14.04f*sqrtf(fmaxf(a,1e-12f)))*(1.0f/6.0f);
  int ii = (int)f; ii %= G; if (ii<0) ii += G;
  idx = ii;
}

// ---------- sample -> tile footprint ----------
__device__ __forceinline__ void tile_span(const float* __restrict__ ktraj, int m,
                                          int& tx0, int& tx1, int& ty0, int& ty1){
  const float PI2 = 6.28318530717958647692f;
  float tmx = ktraj[m]        * ((float)GX/PI2);
  float tmy = ktraj[MPTS + m] * ((float)GY/PI2);
  int bx = (int)floorf(tmx - 3.0f), by = (int)floorf(tmy - 3.0f);
  int ix0 = ((bx + 1) % GX + GX) % GX;
  int iy0 = ((by + 1) % GY + GY) % GY;
  tx0 = ix0 >> 5;            tx1 = ((ix0 + 5) % GX) >> 5;
  ty0 = iy0 >> 5;            ty1 = ((iy0 + 5) % GY) >> 5;
}

// ---------- ydc[m][c][2] = kspace * dcomp ----------
__global__ void make_ydc(const float* __restrict__ kr, const float* __restrict__ ki,
                         const float* __restrict__ dc, float* __restrict__ ydc){
  int m = blockIdx.x*256 + threadIdx.x;
  if (m >= MPTS) return;
  float d = dc[m];
  #pragma unroll
  for (int c=0;c<NC;++c){
    ydc[((size_t)m*NC + c)*2    ] = kr[(size_t)c*MPTS + m]*d;
    ydc[((size_t)m*NC + c)*2 + 1] = ki[(size_t)c*MPTS + m]*d;
  }
}

// ---------- bin build ----------
__global__ void bin_hist(const float* __restrict__ ktraj, int* __restrict__ bhist){
  int m = blockIdx.x*256 + threadIdx.x;
  if (m >= MPTS) return;
  int tx0,tx1,ty0,ty1; tile_span(ktraj,m,tx0,tx1,ty0,ty1);
  atomicAdd(&bhist[tx0*NTY+ty0],1);
  if (tx1!=tx0) atomicAdd(&bhist[tx1*NTY+ty0],1);
  if (ty1!=ty0){
    atomicAdd(&bhist[tx0*NTY+ty1],1);
    if (tx1!=tx0) atomicAdd(&bhist[tx1*NTY+ty1],1);
  }
}

__global__ __launch_bounds__(256) void bin_scan(const int* __restrict__ bhist,
                                                int* __restrict__ bstart,
                                                int* __restrict__ bcur){
  __shared__ int ps[256];
  int t = threadIdx.x;
  int v[5]; int s = 0;
  #pragma unroll
  for (int j=0;j<5;++j){ int i = t*5+j; v[j] = (i<NTILE)?bhist[i]:0; s += v[j]; }
  ps[t] = s; __syncthreads();
  for (int off=1; off<256; off<<=1){
    int x = (t>=off) ? ps[t-off] : 0;
    __syncthreads();
    ps[t] += x;
    __syncthreads();
  }
  int run = (t==0) ? 0 : ps[t-1];
  #pragma unroll
  for (int j=0;j<5;++j){
    int i = t*5+j;
    if (i<NTILE){ bstart[i]=run; bcur[i]=run; }
    run += v[j];
  }
}

__global__ void bin_fill(const float* __restrict__ ktraj, int* __restrict__ bcur,
                         int* __restrict__ bent){
  int m = blockIdx.x*256 + threadIdx.x;
  if (m >= MPTS) return;
  int tx0,tx1,ty0,ty1; tile_span(ktraj,m,tx0,tx1,ty0,ty1);
  int p = atomicAdd(&bcur[tx0*NTY+ty0],1); bent[p] = m;
  if (tx1!=tx0){ p = atomicAdd(&bcur[tx1*NTY+ty0],1); bent[p] = m; }
  if (ty1!=ty0){
    p = atomicAdd(&bcur[tx0*NTY+ty1],1); bent[p] = m;
    if (tx1!=tx0){ p = atomicAdd(&bcur[tx1*NTY+ty1],1); bent[p] = m; }
  }
}

// ---------- tile scatter, wave-per-entry: lane = tap (a,b) of the 6x6 stencil ----------
template<int BC>
__global__ __launch_bounds__(256) void tile_scatter(const float* __restrict__ ktraj,
                                                    const float* __restrict__ ydc,
                                                    const int* __restrict__ bstart,
                                                    const int* __restrict__ bend,
                                                    const int* __restrict__ bent,
                                                    bf16* __restrict__ A1, int c0){
  int tile = blockIdx.x;
  int tx = tile / NTY, ty = tile - tx*NTY;
  int x0 = tx*32, y0 = ty*32;
  __shared__ float lr[BC][32][33];
  __shared__ float li[BC][32][33];
  int t = threadIdx.x;
  int lane = t & 63, wid = t >> 6;
  float* lrf = &lr[0][0][0];
  float* lif = &li[0][0][0];
  for (int i=t; i<BC*32*33; i+=256){ lrf[i]=0.f; lif[i]=0.f; }
  __syncthreads();

  const float PI2 = 6.28318530717958647692f;
  int a = lane / 6, b = lane - a*6;          // valid taps: lane < 36
  int beg = bstart[tile], end = bend[tile];
  for (int e = beg + wid; e < end; e += 4){
    int m = bent[e];                          // wave-uniform
    float tmx = ktraj[m]        * ((float)GX/PI2);
    float tmy = ktraj[MPTS + m] * ((float)GY/PI2);
    float bx = floorf(tmx - 3.0f), by = floorf(tmy - 3.0f);
    float wxa, wyb; int ixa, iyb;
    kb_tap(tmx, bx, a, GX, wxa, ixa);
    kb_tap(tmy, by, b, GY, wyb, iyb);
    float w = wxa * wyb;
    int lx = ixa - x0, ly = iyb - y0;
    bool in = (lane < 36) && ((unsigned)lx < 32u) && ((unsigned)ly < 32u);
    const float* yp = ydc + ((size_t)m*NC + c0)*2;   // wave-uniform
    #pragma unroll
    for (int c=0;c<BC;++c){
      float yr = yp[2*c], yi = yp[2*c+1];
      if (in){
        atomicAdd(&lr[c][lx][ly], w*yr);
        atomicAdd(&li[c][lx][ly], w*yi);
      }
    }
  }
  __syncthreads();

  // write-out (ky in [y0, y0+32) covers the 948..959 zero padding on last tile)
  for (int i=t; i<BC*32*32; i+=256){
    int c  = i >> 10;
    int r  = (i >> 5) & 31;
    int ly = i & 31;
    int kx = x0 + r, ky = y0 + ly;
    size_t base = ((size_t)(c*GX + kx)*2) * K1;
    A1[base + ky]      = (bf16)lr[c][r][ly];
    A1[base + K1 + ky] = (bf16)li[c][r][ly];
  }
}

// ---------- twiddle gen: B1 [N1G][K1]: rows 2n+p (n<=160), cols ky ----------
__global__ void gen_B1(bf16* __restrict__ B1){
  int i = blockIdx.x*256 + threadIdx.x;
  if (i >= N1G*K1) return;
  int nr = i / K1, k = i - nr*K1;
  int n = nr >> 1, p = nr & 1;
  float v = 0.f;
  if (n <= 160 && k < GY){
    int rem = (k * n) % GY;
    float ang = 6.28318530717958647692f * (float)rem / (float)GY;
    float s, c; sincosf(ang, &s, &c);
    v = p ? s : c;
  }
  B1[i] = (bf16)v;
}

// ---------- twiddle gen: W2t [N2][K2] ----------
__global__ void gen_W2t(bf16* __restrict__ W2t){
  int i = blockIdx.x*256 + threadIdx.x;
  if (i >= N2*K2) return;
  int n = i / K2, k = i - n*K2;
  float v = 0.f;
  if (n < CROPN){
    int part = k / 1280, kx = k - part*1280;
    int nx = (n < 160) ? (1120 + n) : (n - 160);
    int rem = (kx * nx) % GX;
    float ang = 6.28318530717958647692f * (float)rem / (float)GX;
    float s, c; sincosf(ang, &s, &c);
    v = part ? s : c;
  }
  W2t[i] = (bf16)v;
}

// ---------- pack C1 (F_gr, F_gi) -> A2 bf16 [bc*640][K2], Hermitian reconstruct ----------
__global__ void pack_A2(const float* __restrict__ C1, bf16* __restrict__ A2, int total){
  int i = blockIdx.x*256 + threadIdx.x;
  if (i >= total) return;
  int kg  = i % (K2/8);
  int mr2 = i / (K2/8);
  int cl = mr2 / 640;
  int nn = mr2 - cl*640;
  int q = nn >> 1, ri = nn & 1;
  int k0 = kg*8;
  int part = k0 / 1280, kx0 = k0 - part*1280;
  int nyv = q - 160;
  int n = (nyv >= 0) ? nyv : -nyv;
  bf16x8 ov;
  #pragma unroll
  for (int j=0;j<8;++j){
    int kx = kx0 + j;
    const float* r0 = C1 + ((size_t)(cl*GX + kx)*2) * N1G;
    const float* r1 = r0 + N1G;
    float R0 = r0[2*n], I0 = r0[2*n+1];
    float R1 = r1[2*n], I1 = r1[2*n+1];
    float tre, tim;
    if (nyv >= 0){ tre = R0 - I1; tim = I0 + R1; }
    else         { tre = R0 + I1; tim = R1 - I0; }
    float v = (ri == 0) ? (part == 0 ? tre : -tim)
                        : (part == 0 ? tim :  tre);
    ov[j] = (bf16)v;
  }
  *(bf16x8*)(A2 + (size_t)mr2*K2 + k0) = ov;
}

// ---------- bf16 GEMM: C[m][n] = sum_k A[m][k]*B[n][k] ----------
#define BM 128
#define BN 128
#define BK 32
#define LDT 40

__global__ __launch_bounds__(256) void gemm_bt(const bf16* __restrict__ A,
                                               const bf16* __restrict__ B,
                                               float* __restrict__ C,
                                               int K, int ldc){
  __shared__ bf16 As[BM*LDT];
  __shared__ bf16 Bs[BM*LDT];
  int t = threadIdx.x;
  int lane = t & 63;
  int wave = t >> 6;
  int wm = wave >> 1, wn = wave & 1;
  size_t tileM = (size_t)blockIdx.x * BM;
  size_t tileN = (size_t)blockIdx.y * BN;

  const bf16* Ab = A + tileM * K;
  const bf16* Bb = B + tileN * K;

  f32x4 zero = {0.f, 0.f, 0.f, 0.f};
  f32x4 acc[4][4];
  #pragma unroll
  for (int m=0;m<4;++m)
    #pragma unroll
    for (int n=0;n<4;++n) acc[m][n] = zero;

  int r0 = t >> 2;
  int kc = (t & 3) * 8;
  size_t aoff = (size_t)r0 * K + kc;

  bf16x8 a0 = *(const bf16x8*)(Ab + aoff);
  bf16x8 a1 = *(const bf16x8*)(Ab + aoff + (size_t)64*K);
  bf16x8 b0 = *(const bf16x8*)(Bb + aoff);
  bf16x8 b1 = *(const bf16x8*)(Bb + aoff + (size_t)64*K);

  int lr = lane & 15, lk = (lane >> 4) * 8;

  for (int kt = 0; kt < K; kt += BK){
    __syncthreads();
    *(bf16x8*)(As + r0*LDT + kc)      = a0;
    *(bf16x8*)(As + (r0+64)*LDT + kc) = a1;
    *(bf16x8*)(Bs + r0*LDT + kc)      = b0;
    *(bf16x8*)(Bs + (r0+64)*LDT + kc) = b1;
    __syncthreads();

    bool more = (kt + BK) < K;
    if (more){
      size_t o = aoff + kt + BK;
      a0 = *(const bf16x8*)(Ab + o);
      a1 = *(const bf16x8*)(Ab + o + (size_t)64*K);
      b0 = *(const bf16x8*)(Bb + o);
      b1 = *(const bf16x8*)(Bb + o + (size_t)64*K);
    }

    bf16x8 af[4], bg[4];
    #pragma unroll
    for (int m=0;m<4;++m)
      af[m] = *(const bf16x8*)(As + (wm*64 + m*16 + lr)*LDT + lk);
    #pragma unroll
    for (int n=0;n<4;++n)
      bg[n] = *(const bf16x8*)(Bs + (wn*64 + n*16 + lr)*LDT + lk);
    #pragma unroll
    for (int m=0;m<4;++m)
      #pragma unroll
      for (int n=0;n<4;++n)
        acc[m][n] = __builtin_amdgcn_mfma_f32_16x16x32_bf16(af[m], bg[n], acc[m][n], 0, 0, 0);
  }

  int lrow = (lane >> 4) * 4;
  #pragma unroll
  for (int m=0;m<4;++m)
    #pragma unroll
    for (int n=0;n<4;++n){
      size_t row = tileM + wm*64 + m*16 + lrow;
      size_t col = tileN + wn*64 + n*16 + lr;
      #pragma unroll
      for (int r=0;r<4;++r)
        C[(row + r)*(size_t)ldc + col] = acc[m][n][r];
    }
}

// ---------- coil combine into accum ----------
__global__ void combine(const float* __restrict__ C2,
                        const float* __restrict__ smr, const float* __restrict__ smi,
                        float* __restrict__ accum, int c0, int bc){
  int i = blockIdx.x*256 + threadIdx.x;
  if (i >= CROPN*CROPN) return;
  int r = i / CROPN, q = i - r*CROPN;
  float ar = 0.f, ai = 0.f;
  for (int cl=0; cl<bc; ++cl){
    float re = C2[((size_t)cl*640 + 2*q    )*N2 + r];
    float im = C2[((size_t)cl*640 + 2*q + 1)*N2 + r];
    size_t sidx = ((size_t)(c0+cl)*HH + (160+r))*WW + (77+q);
    float sr = smr[sidx], si = smi[sidx];
    ar += sr*re + si*im;
    ai += sr*im - si*re;
  }
  accum[2*i] += ar; accum[2*i+1] += ai;
}

// ---------- deapodization + magnitude ----------
__device__ __forceinline__ float deapod_f(float n, float G){
  float x = 3.14159265358979323846f * 6.0f * n / G;
  float z = 197.1216f - x*x;
  float sz = sqrtf(fabsf(z) + 1e-12f);
  float K;
  if (z > 0.0f){
    float e = __expf(sz);
    K = (e - 1.0f/e)*0.5f/sz;
  } else {
    K = __sinf(sz)/sz;
  }
  return 1.0f/K;
}

__global__ void final_mag(const float* __restrict__ accum, float* __restrict__ out){
  int i = blockIdx.x*256 + threadIdx.x;
  if (i >= CROPN*CROPN) return;
  int r  = i / CROPN;
  int cc = i - r*CROPN;
  float dx = deapod_f((float)(r  - 160), (float)GX);
  float dy = deapod_f((float)(cc - 160), (float)GY);
  float re = accum[2*i], im = accum[2*i+1];
  out[i] = sqrtf(re*re + im*im) * dx * dy;
}

extern "C" void kernel_launch(void* const* d_in, const int* in_sizes, int n_in,
                              void* d_out, int out_size, void* d_ws, size_t ws_size,
                              hipStream_t stream){
  const float* kr    = (const float*)d_in[0];
  const float* ki    = (const float*)d_in[1];
  const float* ktraj = (const float*)d_in[2];
  const float* dc    = (const float*)d_in[3];
  const float* smr   = (const float*)d_in[4];
  const float* smi   = (const float*)d_in[5];
  float* out = (float*)d_out;

  // ---- workspace carve (bytes) ----
  const size_t acc_b   = (size_t)CROPN*CROPN*2*4;    //   819,200
  const size_t B1_b    = (size_t)N1G*K1*2;           //   737,280
  const size_t W2t_b   = (size_t)N2*K2*2;            // 1,966,080
  const size_t ydc_b   = (size_t)MPTS*NC*2*4;        // 4,915,200
  const size_t bh_b    = 8192;
  const size_t bent_b  = (size_t)MAXENT*4;           //   655,360
  const size_t fixed_b = acc_b+B1_b+W2t_b+ydc_b+3*bh_b+bent_b;   // ~9.1 MB

  const size_t A1_pc   = (size_t)GX*2*K1*2;          // 4,915,200 (A2 aliases A1)
  const size_t C1_pc   = (size_t)GX*2*N1G*4;         // 3,932,160
  const size_t C2_pc   = (size_t)640*N2*4;           //   983,040
  const size_t percoil = A1_pc + C1_pc + C2_pc;      // 9,830,400

  int bc = 1;
  if (ws_size > fixed_b + percoil){
    size_t b = (ws_size - fixed_b) / percoil;
    bc = (int)(b > 8 ? 8 : b);
    if (bc < 1) bc = 1;
  }

  char* p = (char*)d_ws;
  float* accum  = (float*)p; p += acc_b;
  bf16*  B1     = (bf16*)p;  p += B1_b;
  bf16*  W2t    = (bf16*)p;  p += W2t_b;
  float* ydc    = (float*)p; p += ydc_b;
  int*   bhist  = (int*)p;   p += bh_b;
  int*   bstart = (int*)p;   p += bh_b;
  int*   bcur   = (int*)p;   p += bh_b;
  int*   bent   = (int*)p;   p += bent_b;
  bf16*  A1     = (bf16*)p;
  bf16*  A2     = (bf16*)p;  p += (size_t)bc*A1_pc;   // A2 aliases A1 (dead after GEMM1)
  float* C1     = (float*)p; p += (size_t)bc*C1_pc;
  float* C2     = (float*)p; p += (size_t)bc*C2_pc;

  // ---- one-time builds ----
  make_ydc<<<(MPTS+255)/256, 256, 0, stream>>>(kr, ki, dc, ydc);
  hipMemsetAsync(bhist, 0, NTILE*4, stream);
  bin_hist<<<(MPTS+255)/256, 256, 0, stream>>>(ktraj, bhist);
  bin_scan<<<1, 256, 0, stream>>>(bhist, bstart, bcur);
  bin_fill<<<(MPTS+255)/256, 256, 0, stream>>>(ktraj, bcur, bent);
  gen_B1<<<(N1G*K1+255)/256, 256, 0, stream>>>(B1);
  gen_W2t<<<(N2*K2+255)/256, 256, 0, stream>>>(W2t);
  hipMemsetAsync(accum, 0, acc_b, stream);

  // ---- per coil-batch pipeline ----
  for (int c0 = 0; c0 < NC; c0 += bc){
    int nb = NC - c0; if (nb > bc) nb = bc;

    switch (nb){
      case 1: tile_scatter<1><<<NTILE,256,0,stream>>>(ktraj,ydc,bstart,bcur,bent,A1,c0); break;
      case 2: tile_scatter<2><<<NTILE,256,0,stream>>>(ktraj,ydc,bstart,bcur,bent,A1,c0); break;
      case 3: tile_scatter<3><<<NTILE,256,0,stream>>>(ktraj,ydc,bstart,bcur,bent,A1,c0); break;
      case 4: tile_scatter<4><<<NTILE,256,0,stream>>>(ktraj,ydc,bstart,bcur,bent,A1,c0); break;
      case 5: tile_scatter<5><<<NTILE,256,0,stream>>>(ktraj,ydc,bstart,bcur,bent,A1,c0); break;
      case 6: tile_scatter<6><<<NTILE,256,0,stream>>>(ktraj,ydc,bstart,bcur,bent,A1,c0); break;
      case 7: tile_scatter<7><<<NTILE,256,0,stream>>>(ktraj,ydc,bstart,bcur,bent,A1,c0); break;
      default: tile_scatter<8><<<NTILE,256,0,stream>>>(ktraj,ydc,bstart,bcur,bent,A1,c0); break;
    }

    // GEMM1: [nb*2560][960] x [384][960]^T -> C1 [nb*2560][384]
    gemm_bt<<<dim3(nb*(GX*2/BM), N1G/BN), 256, 0, stream>>>(A1, B1, C1, K1, N1G);

    int tot2 = nb*640*(K2/8);
    pack_A2<<<(tot2+255)/256, 256, 0, stream>>>(C1, A2, tot2);

    // GEMM2: [nb*640][2560] x [384][2560]^T -> C2 [nb*640][384]
    gemm_bt<<<dim3(nb*(640/BM), N2/BN), 256, 0, stream>>>(A2, W2t, C2, K2, N2);

    combine<<<(CROPN*CROPN+255)/256, 256, 0, stream>>>(C2, smr, smi, accum, c0, nb);
  }
  final_mag<<<(CROPN*CROPN+255)/256, 256, 0, stream>>>(accum, out);
}

// Round 6
// 343.376 us; speedup vs baseline: 2.1280x; 2.0393x over previous
//
#include <hip/hip_runtime.h>

typedef __bf16 bf16;
typedef __attribute__((ext_vector_type(8))) __bf16 bf16x8;
typedef __attribute__((ext_vector_type(4))) __bf16 bf16x4;
typedef __attribute__((ext_vector_type(4))) float f32x4;

#define MPTS 40960
#define NC 15
#define GX 1280
#define GY 948
#define HH 640
#define WW 474
#define CROPN 320

#define K1 960    // ky padded 948->960, real input
#define N1G 384   // rows 2n+p, n<=160 used (322), padded to 384
#define K2 2560   // [tr(1280 kx) | ti(1280)]
#define N2 384    // 320 image rows padded to 384

#define NTX 40
#define NTY 30
#define NTILE (NTX*NTY)   // 1200
#define MAXENT (MPTS*4)
#define CHUNK 128

// ---------- modified Bessel I0 (A&S 9.8.1 / 9.8.2) ----------
__device__ __forceinline__ float i0f_dev(float x){
  if (x < 3.75f){
    float t = x*(1.0f/3.75f); t *= t;
    return 1.0f + t*(3.5156229f + t*(3.0899424f + t*(1.2067492f +
                 t*(0.2659732f + t*(0.0360768f + t*0.0045813f)))));
  } else {
    float t = 3.75f/x;
    float p = 0.39894228f + t*(0.01328592f + t*(0.00225319f + t*(-0.00157565f +
              t*(0.00916281f + t*(-0.02057706f + t*(0.02635537f +
              t*(-0.01647633f + t*0.00392377f)))))));
    return __expf(x)*rsqrtf(x)*p;
  }
}

// KB weight from (exact) tap distance u, |u|<3
__device__ __forceinline__ float kb_w(float u){
  float a = 1.0f - u*u*(1.0f/9.0f);
  return i0f_dev(14.04f*sqrtf(fmaxf(a, 0.0f)))*(1.0f/6.0f);
}

// ---------- sample -> tile footprint ----------
__device__ __forceinline__ void tile_span(const float* __restrict__ ktraj, int m,
                                          int& tx0, int& tx1, int& ty0, int& ty1){
  const float PI2 = 6.28318530717958647692f;
  float tmx = ktraj[m]        * ((float)GX/PI2);
  float tmy = ktraj[MPTS + m] * ((float)GY/PI2);
  int bx = (int)floorf(tmx - 3.0f), by = (int)floorf(tmy - 3.0f);
  int ix0 = ((bx + 1) % GX + GX) % GX;
  int iy0 = ((by + 1) % GY + GY) % GY;
  tx0 = ix0 >> 5;            tx1 = ((ix0 + 5) % GX) >> 5;
  ty0 = iy0 >> 5;            ty1 = ((iy0 + 5) % GY) >> 5;
}

// ---------- prep: ydc = kspace*dcomp, and tile histogram ----------
__global__ void prep(const float* __restrict__ kr, const float* __restrict__ ki,
                     const float* __restrict__ dc, const float* __restrict__ ktraj,
                     float* __restrict__ ydc, int* __restrict__ bhist){
  int m = blockIdx.x*256 + threadIdx.x;
  if (m >= MPTS) return;
  float d = dc[m];
  #pragma unroll
  for (int c=0;c<NC;++c){
    ydc[((size_t)m*NC + c)*2    ] = kr[(size_t)c*MPTS + m]*d;
    ydc[((size_t)m*NC + c)*2 + 1] = ki[(size_t)c*MPTS + m]*d;
  }
  int tx0,tx1,ty0,ty1; tile_span(ktraj,m,tx0,tx1,ty0,ty1);
  atomicAdd(&bhist[tx0*NTY+ty0],1);
  if (tx1!=tx0) atomicAdd(&bhist[tx1*NTY+ty0],1);
  if (ty1!=ty0){
    atomicAdd(&bhist[tx0*NTY+ty1],1);
    if (tx1!=tx0) atomicAdd(&bhist[tx1*NTY+ty1],1);
  }
}

__global__ __launch_bounds__(256) void bin_scan(const int* __restrict__ bhist,
                                                int* __restrict__ bstart,
                                                int* __restrict__ bcur){
  __shared__ int ps[256];
  int t = threadIdx.x;
  int v[5]; int s = 0;
  #pragma unroll
  for (int j=0;j<5;++j){ int i = t*5+j; v[j] = (i<NTILE)?bhist[i]:0; s += v[j]; }
  ps[t] = s; __syncthreads();
  for (int off=1; off<256; off<<=1){
    int x = (t>=off) ? ps[t-off] : 0;
    __syncthreads();
    ps[t] += x;
    __syncthreads();
  }
  int run = (t==0) ? 0 : ps[t-1];
  #pragma unroll
  for (int j=0;j<5;++j){
    int i = t*5+j;
    if (i<NTILE){ bstart[i]=run; bcur[i]=run; }
    run += v[j];
  }
}

__global__ void bin_fill(const float* __restrict__ ktraj, int* __restrict__ bcur,
                         int* __restrict__ bent){
  int m = blockIdx.x*256 + threadIdx.x;
  if (m >= MPTS) return;
  int tx0,tx1,ty0,ty1; tile_span(ktraj,m,tx0,tx1,ty0,ty1);
  int p = atomicAdd(&bcur[tx0*NTY+ty0],1); bent[p] = m;
  if (tx1!=tx0){ p = atomicAdd(&bcur[tx1*NTY+ty0],1); bent[p] = m; }
  if (ty1!=ty0){
    p = atomicAdd(&bcur[tx0*NTY+ty1],1); bent[p] = m;
    if (tx1!=tx0){ p = atomicAdd(&bcur[tx1*NTY+ty1],1); bent[p] = m; }
  }
}

// ---------- tile gather: thread owns 4 cells; samples staged in LDS ----------
template<int BC>
__global__ __launch_bounds__(256) void tile_gather(const float* __restrict__ ktraj,
                                                   const float* __restrict__ ydc,
                                                   const int* __restrict__ bstart,
                                                   const int* __restrict__ bend,
                                                   const int* __restrict__ bent,
                                                   bf16* __restrict__ A1, int c0){
  int tile = blockIdx.x;
  int tx = tile / NTY, ty = tile - tx*NTY;
  int x0 = tx*32, y0 = ty*32;
  int t = threadIdx.x;
  int kxl = t >> 3;           // 0..31
  int ky0l = (t & 7) * 4;     // 0,4,..,28
  float kxf = (float)(x0 + kxl);
  float kyf[4], maskq[4];
  #pragma unroll
  for (int q=0;q<4;++q){
    int ky = y0 + ky0l + q;
    kyf[q] = (float)ky;
    maskq[q] = (ky < GY) ? 1.0f : 0.0f;   // zero the 948..959 padding at write
  }

  __shared__ float stx[CHUNK], sty[CHUNK];
  __shared__ float sy[CHUNK][2*BC];

  float accr[4][BC], acci[4][BC];
  #pragma unroll
  for (int q=0;q<4;++q)
    #pragma unroll
    for (int c=0;c<BC;++c){ accr[q][c]=0.f; acci[q][c]=0.f; }

  const float PI2 = 6.28318530717958647692f;
  int beg = bstart[tile], end = bend[tile];
  for (int s0 = beg; s0 < end; s0 += CHUNK){
    int ns = end - s0; if (ns > CHUNK) ns = CHUNK;
    __syncthreads();
    for (int i=t; i<ns; i+=256){
      int m = bent[s0+i];
      stx[i] = ktraj[m]        * ((float)GX/PI2);
      sty[i] = ktraj[MPTS + m] * ((float)GY/PI2);
    }
    for (int i=t; i<ns*2*BC; i+=256){
      int s = i / (2*BC), f = i - s*(2*BC);
      int m = bent[s0+s];
      sy[s][f] = ydc[((size_t)m*NC + c0)*2 + f];
    }
    __syncthreads();
    for (int s=0; s<ns; ++s){
      float dx = stx[s] - kxf;
      dx -= (float)GX * rintf(dx * (1.0f/(float)GX));
      if (fabsf(dx) < 3.0f){
        float wx = kb_w(dx);
        float tmy = sty[s];
        float yr[BC], yi[BC];
        #pragma unroll
        for (int c=0;c<BC;++c){ yr[c] = sy[s][2*c]; yi[c] = sy[s][2*c+1]; }
        #pragma unroll
        for (int q=0;q<4;++q){
          float dy = tmy - kyf[q];
          dy -= (float)GY * rintf(dy * (1.0f/(float)GY));
          if (fabsf(dy) < 3.0f){
            float w = wx * kb_w(dy);
            #pragma unroll
            for (int c=0;c<BC;++c){
              accr[q][c] = fmaf(w, yr[c], accr[q][c]);
              acci[q][c] = fmaf(w, yi[c], acci[q][c]);
            }
          }
        }
      }
    }
  }

  int kx = x0 + kxl;
  int ky = y0 + ky0l;
  #pragma unroll
  for (int c=0;c<BC;++c){
    bf16x4 vr, vi;
    #pragma unroll
    for (int q=0;q<4;++q){
      vr[q] = (bf16)(accr[q][c]*maskq[q]);
      vi[q] = (bf16)(acci[q][c]*maskq[q]);
    }
    size_t base = ((size_t)((c*GX + kx)*2)) * K1;
    *(bf16x4*)(A1 + base + ky)      = vr;
    *(bf16x4*)(A1 + base + K1 + ky) = vi;
  }
}

// ---------- twiddle gen (B1 [N1G][K1] and W2t [N2][K2] in one kernel) ----------
#define B1_ELEMS (N1G*K1)
#define W2_ELEMS (N2*K2)
__global__ void gen_tw(bf16* __restrict__ B1, bf16* __restrict__ W2t){
  int i = blockIdx.x*256 + threadIdx.x;
  if (i < B1_ELEMS){
    int nr = i / K1, k = i - nr*K1;
    int n = nr >> 1, p = nr & 1;
    float v = 0.f;
    if (n <= 160 && k < GY){
      int rem = (k * n) % GY;
      float ang = 6.28318530717958647692f * (float)rem / (float)GY;
      float s, c; sincosf(ang, &s, &c);
      v = p ? s : c;
    }
    B1[i] = (bf16)v;
  } else if (i < B1_ELEMS + W2_ELEMS){
    int j = i - B1_ELEMS;
    int n = j / K2, k = j - n*K2;
    float v = 0.f;
    if (n < CROPN){
      int part = k / 1280, kx = k - part*1280;
      int nx = (n < 160) ? (1120 + n) : (n - 160);
      int rem = (kx * nx) % GX;
      float ang = 6.28318530717958647692f * (float)rem / (float)GX;
      float s, c; sincosf(ang, &s, &c);
      v = part ? s : c;
    }
    W2t[j] = (bf16)v;
  }
}

// ---------- pack C1t -> A2, Hermitian reconstruct, contiguous reads ----------
// C1t [384][ldc1]: row 2n = cos-comp, row 2n+1 = sin-comp; col mc=(cl*GX+kx)*2+half
__global__ void pack_A2t(const float* __restrict__ C1t, bf16* __restrict__ A2,
                         int nb, int ldc1){
  int i = blockIdx.x*256 + threadIdx.x;
  if (i >= nb*161*160) return;
  int kxg = i % 160;
  int rem = i / 160;
  int n   = rem % 161;
  int cl  = rem / 161;
  int kx0 = kxg*8;
  int cb  = (cl*GX + kx0)*2;
  const float4* pr = (const float4*)(C1t + (size_t)(2*n)*ldc1 + cb);
  const float4* ps = (const float4*)(C1t + (size_t)(2*n+1)*ldc1 + cb);
  float CR[8], CI[8], SR[8], SI[8];
  #pragma unroll
  for (int j=0;j<4;++j){
    float4 c4 = pr[j], s4 = ps[j];
    CR[2*j] = c4.x; CI[2*j] = c4.y; CR[2*j+1] = c4.z; CI[2*j+1] = c4.w;
    SR[2*j] = s4.x; SI[2*j] = s4.y; SR[2*j+1] = s4.z; SI[2*j+1] = s4.w;
  }
  if (n <= 159){                       // q+ = 160+n
    bf16x8 t0, t1, m1;
    #pragma unroll
    for (int j=0;j<8;++j){
      float a = CR[j] - SI[j];         // tre+
      float b = SR[j] + CI[j];         // tim+
      t0[j] = (bf16)a; t1[j] = (bf16)b; m1[j] = (bf16)(-b);
    }
    size_t r0 = ((size_t)(cl*640 + 2*(160+n)))*K2;
    *(bf16x8*)(A2 + r0 + kx0)             = t0;   // ri0 part0: tre
    *(bf16x8*)(A2 + r0 + 1280 + kx0)      = m1;   // ri0 part1: -tim
    *(bf16x8*)(A2 + r0 + K2 + kx0)        = t1;   // ri1 part0: tim
    *(bf16x8*)(A2 + r0 + K2 + 1280 + kx0) = t0;   // ri1 part1: tre
  }
  if (n >= 1){                         // q- = 160-n
    bf16x8 t0, t1, m1;
    #pragma unroll
    for (int j=0;j<8;++j){
      float a = CR[j] + SI[j];         // tre-
      float b = CI[j] - SR[j];         // tim-
      t0[j] = (bf16)a; t1[j] = (bf16)b; m1[j] = (bf16)(-b);
    }
    size_t r0 = ((size_t)(cl*640 + 2*(160-n)))*K2;
    *(bf16x8*)(A2 + r0 + kx0)             = t0;
    *(bf16x8*)(A2 + r0 + 1280 + kx0)      = m1;
    *(bf16x8*)(A2 + r0 + K2 + kx0)        = t1;
    *(bf16x8*)(A2 + r0 + K2 + 1280 + kx0) = t0;
  }
}

// ---------- bf16 GEMM, 128x128 tile: C[m][n] = sum_k A[m][k]*B[n][k] ----------
#define BM 128
#define BN 128
#define BK 32
#define LDT 40

__global__ __launch_bounds__(256) void gemm_bt(const bf16* __restrict__ A,
                                               const bf16* __restrict__ B,
                                               float* __restrict__ C,
                                               int K, int ldc){
  __shared__ bf16 As[BM*LDT];
  __shared__ bf16 Bs[BM*LDT];
  int t = threadIdx.x;
  int lane = t & 63;
  int wave = t >> 6;
  int wm = wave >> 1, wn = wave & 1;
  size_t tileM = (size_t)blockIdx.x * BM;
  size_t tileN = (size_t)blockIdx.y * BN;

  const bf16* Ab = A + tileM * K;
  const bf16* Bb = B + tileN * K;

  f32x4 zero = {0.f, 0.f, 0.f, 0.f};
  f32x4 acc[4][4];
  #pragma unroll
  for (int m=0;m<4;++m)
    #pragma unroll
    for (int n=0;n<4;++n) acc[m][n] = zero;

  int r0 = t >> 2;
  int kc = (t & 3) * 8;
  size_t aoff = (size_t)r0 * K + kc;

  bf16x8 a0 = *(const bf16x8*)(Ab + aoff);
  bf16x8 a1 = *(const bf16x8*)(Ab + aoff + (size_t)64*K);
  bf16x8 b0 = *(const bf16x8*)(Bb + aoff);
  bf16x8 b1 = *(const bf16x8*)(Bb + aoff + (size_t)64*K);

  int lr = lane & 15, lk = (lane >> 4) * 8;

  for (int kt = 0; kt < K; kt += BK){
    __syncthreads();
    *(bf16x8*)(As + r0*LDT + kc)      = a0;
    *(bf16x8*)(As + (r0+64)*LDT + kc) = a1;
    *(bf16x8*)(Bs + r0*LDT + kc)      = b0;
    *(bf16x8*)(Bs + (r0+64)*LDT + kc) = b1;
    __syncthreads();

    bool more = (kt + BK) < K;
    if (more){
      size_t o = aoff + kt + BK;
      a0 = *(const bf16x8*)(Ab + o);
      a1 = *(const bf16x8*)(Ab + o + (size_t)64*K);
      b0 = *(const bf16x8*)(Bb + o);
      b1 = *(const bf16x8*)(Bb + o + (size_t)64*K);
    }

    bf16x8 af[4], bg[4];
    #pragma unroll
    for (int m=0;m<4;++m)
      af[m] = *(const bf16x8*)(As + (wm*64 + m*16 + lr)*LDT + lk);
    #pragma unroll
    for (int n=0;n<4;++n)
      bg[n] = *(const bf16x8*)(Bs + (wn*64 + n*16 + lr)*LDT + lk);
    #pragma unroll
    for (int m=0;m<4;++m)
      #pragma unroll
      for (int n=0;n<4;++n)
        acc[m][n] = __builtin_amdgcn_mfma_f32_16x16x32_bf16(af[m], bg[n], acc[m][n], 0, 0, 0);
  }

  int lrow = (lane >> 4) * 4;
  #pragma unroll
  for (int m=0;m<4;++m)
    #pragma unroll
    for (int n=0;n<4;++n){
      size_t row = tileM + wm*64 + m*16 + lrow;
      size_t col = tileN + wn*64 + n*16 + lr;
      #pragma unroll
      for (int r=0;r<4;++r)
        C[(row + r)*(size_t)ldc + col] = acc[m][n][r];
    }
}

// ---------- bf16 GEMM, 64x64 tile (for small-M GEMM2 occupancy) ----------
__global__ __launch_bounds__(256) void gemm_bt64(const bf16* __restrict__ A,
                                                 const bf16* __restrict__ B,
                                                 float* __restrict__ C,
                                                 int K, int ldc){
  __shared__ bf16 As[64*LDT];
  __shared__ bf16 Bs[64*LDT];
  int t = threadIdx.x;
  int lane = t & 63;
  int wave = t >> 6;
  int wm = wave >> 1, wn = wave & 1;
  size_t tileM = (size_t)blockIdx.x * 64;
  size_t tileN = (size_t)blockIdx.y * 64;

  const bf16* Ab = A + tileM * K;
  const bf16* Bb = B + tileN * K;

  f32x4 zero = {0.f, 0.f, 0.f, 0.f};
  f32x4 acc[2][2];
  #pragma unroll
  for (int m=0;m<2;++m)
    #pragma unroll
    for (int n=0;n<2;++n) acc[m][n] = zero;

  int r0 = t >> 2;
  int kc = (t & 3) * 8;
  size_t aoff = (size_t)r0 * K + kc;

  bf16x8 a0 = *(const bf16x8*)(Ab + aoff);
  bf16x8 b0 = *(const bf16x8*)(Bb + aoff);

  int lr = lane & 15, lk = (lane >> 4) * 8;

  for (int kt = 0; kt < K; kt += BK){
    __syncthreads();
    *(bf16x8*)(As + r0*LDT + kc) = a0;
    *(bf16x8*)(Bs + r0*LDT + kc) = b0;
    __syncthreads();

    bool more = (kt + BK) < K;
    if (more){
      size_t o = aoff + kt + BK;
      a0 = *(const bf16x8*)(Ab + o);
      b0 = *(const bf16x8*)(Bb + o);
    }

    bf16x8 af[2], bg[2];
    #pragma unroll
    for (int m=0;m<2;++m)
      af[m] = *(const bf16x8*)(As + (wm*32 + m*16 + lr)*LDT + lk);
    #pragma unroll
    for (int n=0;n<2;++n)
      bg[n] = *(const bf16x8*)(Bs + (wn*32 + n*16 + lr)*LDT + lk);
    #pragma unroll
    for (int m=0;m<2;++m)
      #pragma unroll
      for (int n=0;n<2;++n)
        acc[m][n] = __builtin_amdgcn_mfma_f32_16x16x32_bf16(af[m], bg[n], acc[m][n], 0, 0, 0);
  }

  int lrow = (lane >> 4) * 4;
  #pragma unroll
  for (int m=0;m<2;++m)
    #pragma unroll
    for (int n=0;n<2;++n){
      size_t row = tileM + wm*32 + m*16 + lrow;
      size_t col = tileN + wn*32 + n*16 + lr;
      #pragma unroll
      for (int r=0;r<4;++r)
        C[(row + r)*(size_t)ldc + col] = acc[m][n][r];
    }
}

// ---------- coil combine (C2t layout: [r][cl*640 + 2q + ri]) ----------
__global__ void combine(const float* __restrict__ C2t,
                        const float* __restrict__ smr, const float* __restrict__ smi,
                        float* __restrict__ accum, int c0, int bc, int ldc2){
  int i = blockIdx.x*256 + threadIdx.x;
  if (i >= CROPN*CROPN) return;
  int r = i / CROPN, q = i - r*CROPN;
  const float* row = C2t + (size_t)r*ldc2;
  float ar = 0.f, ai = 0.f;
  for (int cl=0; cl<bc; ++cl){
    float re = row[cl*640 + 2*q];
    float im = row[cl*640 + 2*q + 1];
    size_t sidx = ((size_t)(c0+cl)*HH + (160+r))*WW + (77+q);
    float sr = smr[sidx], si = smi[sidx];
    ar += sr*re + si*im;
    ai += sr*im - si*re;
  }
  accum[2*i] += ar; accum[2*i+1] += ai;
}

// ---------- deapodization + magnitude ----------
__device__ __forceinline__ float deapod_f(float n, float G){
  float x = 3.14159265358979323846f * 6.0f * n / G;
  float z = 197.1216f - x*x;
  float sz = sqrtf(fabsf(z) + 1e-12f);
  float K;
  if (z > 0.0f){
    float e = __expf(sz);
    K = (e - 1.0f/e)*0.5f/sz;
  } else {
    K = __sinf(sz)/sz;
  }
  return 1.0f/K;
}

__global__ void final_mag(const float* __restrict__ accum, float* __restrict__ out){
  int i = blockIdx.x*256 + threadIdx.x;
  if (i >= CROPN*CROPN) return;
  int r  = i / CROPN;
  int cc = i - r*CROPN;
  float dx = deapod_f((float)(r  - 160), (float)GX);
  float dy = deapod_f((float)(cc - 160), (float)GY);
  float re = accum[2*i], im = accum[2*i+1];
  out[i] = sqrtf(re*re + im*im) * dx * dy;
}

extern "C" void kernel_launch(void* const* d_in, const int* in_sizes, int n_in,
                              void* d_out, int out_size, void* d_ws, size_t ws_size,
                              hipStream_t stream){
  const float* kr    = (const float*)d_in[0];
  const float* ki    = (const float*)d_in[1];
  const float* ktraj = (const float*)d_in[2];
  const float* dc    = (const float*)d_in[3];
  const float* smr   = (const float*)d_in[4];
  const float* smi   = (const float*)d_in[5];
  float* out = (float*)d_out;

  // ---- workspace carve (bytes) ----
  const size_t acc_b   = (size_t)CROPN*CROPN*2*4;
  const size_t B1_b    = (size_t)N1G*K1*2;
  const size_t W2t_b   = (size_t)N2*K2*2;
  const size_t ydc_b   = (size_t)MPTS*NC*2*4;
  const size_t bh_b    = 8192;
  const size_t bent_b  = (size_t)MAXENT*4;
  const size_t fixed_b = acc_b+B1_b+W2t_b+ydc_b+3*bh_b+bent_b;   // ~9.1 MB

  const size_t A1_pc   = (size_t)GX*2*K1*2;          // 4,915,200 (A2 aliases A1)
  const size_t C1_pc   = (size_t)GX*2*N1G*4;         // 3,932,160
  const size_t C2_pc   = (size_t)640*N2*4;           //   983,040
  const size_t percoil = A1_pc + C1_pc + C2_pc;

  int bc = 1;
  if (ws_size > fixed_b + percoil){
    size_t b = (ws_size - fixed_b) / percoil;
    bc = (int)(b > 8 ? 8 : b);
    if (bc < 1) bc = 1;
  }

  char* p = (char*)d_ws;
  float* accum  = (float*)p; p += acc_b;
  bf16*  B1     = (bf16*)p;  p += B1_b;
  bf16*  W2t    = (bf16*)p;  p += W2t_b;
  float* ydc    = (float*)p; p += ydc_b;
  int*   bhist  = (int*)p;   p += bh_b;
  int*   bstart = (int*)p;   p += bh_b;
  int*   bcur   = (int*)p;   p += bh_b;
  int*   bent   = (int*)p;   p += bent_b;
  bf16*  A1     = (bf16*)p;
  bf16*  A2     = (bf16*)p;  p += (size_t)bc*A1_pc;   // A2 aliases A1 (dead after GEMM1)
  float* C1t    = (float*)p; p += (size_t)bc*C1_pc;
  float* C2t    = (float*)p; p += (size_t)bc*C2_pc;

  // ---- one-time builds ----
  hipMemsetAsync(bhist, 0, NTILE*4, stream);
  prep<<<(MPTS+255)/256, 256, 0, stream>>>(kr, ki, dc, ktraj, ydc, bhist);
  bin_scan<<<1, 256, 0, stream>>>(bhist, bstart, bcur);
  bin_fill<<<(MPTS+255)/256, 256, 0, stream>>>(ktraj, bcur, bent);
  gen_tw<<<(B1_ELEMS+W2_ELEMS+255)/256, 256, 0, stream>>>(B1, W2t);
  hipMemsetAsync(accum, 0, acc_b, stream);

  // ---- per coil-batch pipeline ----
  for (int c0 = 0; c0 < NC; c0 += bc){
    int nb = NC - c0; if (nb > bc) nb = bc;

    switch (nb){
      case 1: tile_gather<1><<<NTILE,256,0,stream>>>(ktraj,ydc,bstart,bcur,bent,A1,c0); break;
      case 2: tile_gather<2><<<NTILE,256,0,stream>>>(ktraj,ydc,bstart,bcur,bent,A1,c0); break;
      case 3: tile_gather<3><<<NTILE,256,0,stream>>>(ktraj,ydc,bstart,bcur,bent,A1,c0); break;
      case 4: tile_gather<4><<<NTILE,256,0,stream>>>(ktraj,ydc,bstart,bcur,bent,A1,c0); break;
      case 5: tile_gather<5><<<NTILE,256,0,stream>>>(ktraj,ydc,bstart,bcur,bent,A1,c0); break;
      case 6: tile_gather<6><<<NTILE,256,0,stream>>>(ktraj,ydc,bstart,bcur,bent,A1,c0); break;
      case 7: tile_gather<7><<<NTILE,256,0,stream>>>(ktraj,ydc,bstart,bcur,bent,A1,c0); break;
      default: tile_gather<8><<<NTILE,256,0,stream>>>(ktraj,ydc,bstart,bcur,bent,A1,c0); break;
    }

    // GEMM1 (operands swapped): C1t[384][nb*2560] = B1 x A1^T
    gemm_bt<<<dim3(N1G/BM, nb*(GX*2/BN)), 256, 0, stream>>>(B1, A1, C1t, K1, nb*2560);

    int tot2 = nb*161*160;
    pack_A2t<<<(tot2+255)/256, 256, 0, stream>>>(C1t, A2, nb, nb*2560);

    // GEMM2 (operands swapped, 64x64 tiles): C2t[384][nb*640] = W2t x A2^T
    gemm_bt64<<<dim3(N2/64, nb*10), 256, 0, stream>>>(W2t, A2, C2t, K2, nb*640);

    combine<<<(CROPN*CROPN+255)/256, 256, 0, stream>>>(C2t, smr, smi, accum, c0, nb, nb*640);
  }
  final_mag<<<(CROPN*CROPN+255)/256, 256, 0, stream>>>(accum, out);
}

// Round 7
// 268.790 us; speedup vs baseline: 2.7186x; 1.2775x over previous
//
#include <hip/hip_runtime.h>

typedef __bf16 bf16;
typedef __attribute__((ext_vector_type(8))) __bf16 bf16x8;
typedef __attribute__((ext_vector_type(4))) __bf16 bf16x4;
typedef __attribute__((ext_vector_type(4))) float f32x4;

#define MPTS 40960
#define NC 15
#define GX 1280
#define GY 948
#define HH 640
#define WW 474
#define CROPN 320

#define K1 960    // ky padded 948->960, real input
#define N1G 384   // rows 2n+p, n<=160 used (322), padded to 384
#define K2 2560   // [tr(1280 kx) | ti(1280)]
#define N2 384    // 320 image rows padded to 384 (only 320 computed)

#define NTX 40
#define NTY 30
#define NTILE (NTX*NTY)   // 1200
#define MAXENT (MPTS*4)
#define CHUNK 128

// ---------- modified Bessel I0 (A&S 9.8.1 / 9.8.2) ----------
__device__ __forceinline__ float i0f_dev(float x){
  if (x < 3.75f){
    float t = x*(1.0f/3.75f); t *= t;
    return 1.0f + t*(3.5156229f + t*(3.0899424f + t*(1.2067492f +
                 t*(0.2659732f + t*(0.0360768f + t*0.0045813f)))));
  } else {
    float t = 3.75f/x;
    float p = 0.39894228f + t*(0.01328592f + t*(0.00225319f + t*(-0.00157565f +
              t*(0.00916281f + t*(-0.02057706f + t*(0.02635537f +
              t*(-0.01647633f + t*0.00392377f)))))));
    return __expf(x)*rsqrtf(x)*p;
  }
}

// KB weight from tap distance u, |u|<3
__device__ __forceinline__ float kb_w(float u){
  float a = 1.0f - u*u*(1.0f/9.0f);
  return i0f_dev(14.04f*sqrtf(fmaxf(a, 0.0f)))*(1.0f/6.0f);
}

// ---------- prep: ydc = kspace*dcomp, KB tap tables, tile histogram ----------
__global__ void prep(const float* __restrict__ kr, const float* __restrict__ ki,
                     const float* __restrict__ dc, const float* __restrict__ ktraj,
                     float* __restrict__ ydc, float* __restrict__ wtab,
                     int2* __restrict__ itab, int* __restrict__ bhist){
  int m = blockIdx.x*256 + threadIdx.x;
  if (m >= MPTS) return;
  float d = dc[m];
  #pragma unroll
  for (int c=0;c<NC;++c){
    ydc[((size_t)m*NC + c)*2    ] = kr[(size_t)c*MPTS + m]*d;
    ydc[((size_t)m*NC + c)*2 + 1] = ki[(size_t)c*MPTS + m]*d;
  }
  const float PI2 = 6.28318530717958647692f;
  float tmx = ktraj[m]        * ((float)GX/PI2);
  float tmy = ktraj[MPTS + m] * ((float)GY/PI2);
  float bx = floorf(tmx - 3.0f), by = floorf(tmy - 3.0f);
  float wx[6], wy[6];
  #pragma unroll
  for (int j=0;j<6;++j){
    wx[j] = kb_w(tmx - (bx + (float)(j+1)));
    wy[j] = kb_w(tmy - (by + (float)(j+1)));
  }
  float4* wt = (float4*)(wtab + (size_t)m*12);
  wt[0] = make_float4(wx[0], wx[1], wx[2], wx[3]);
  wt[1] = make_float4(wx[4], wx[5], wy[0], wy[1]);
  wt[2] = make_float4(wy[2], wy[3], wy[4], wy[5]);
  int ix0 = ((int)bx + 1) % GX; if (ix0 < 0) ix0 += GX;
  int iy0 = ((int)by + 1) % GY; if (iy0 < 0) iy0 += GY;
  itab[m] = make_int2(ix0, iy0);
  int tx0 = ix0 >> 5, tx1 = ((ix0 + 5) % GX) >> 5;
  int ty0 = iy0 >> 5, ty1 = ((iy0 + 5) % GY) >> 5;
  atomicAdd(&bhist[tx0*NTY+ty0],1);
  if (tx1!=tx0) atomicAdd(&bhist[tx1*NTY+ty0],1);
  if (ty1!=ty0){
    atomicAdd(&bhist[tx0*NTY+ty1],1);
    if (tx1!=tx0) atomicAdd(&bhist[tx1*NTY+ty1],1);
  }
}

__global__ __launch_bounds__(256) void bin_scan(const int* __restrict__ bhist,
                                                int* __restrict__ bstart,
                                                int* __restrict__ bcur){
  __shared__ int ps[256];
  int t = threadIdx.x;
  int v[5]; int s = 0;
  #pragma unroll
  for (int j=0;j<5;++j){ int i = t*5+j; v[j] = (i<NTILE)?bhist[i]:0; s += v[j]; }
  ps[t] = s; __syncthreads();
  for (int off=1; off<256; off<<=1){
    int x = (t>=off) ? ps[t-off] : 0;
    __syncthreads();
    ps[t] += x;
    __syncthreads();
  }
  int run = (t==0) ? 0 : ps[t-1];
  #pragma unroll
  for (int j=0;j<5;++j){
    int i = t*5+j;
    if (i<NTILE){ bstart[i]=run; bcur[i]=run; }
    run += v[j];
  }
}

__global__ void bin_fill(const int2* __restrict__ itab, int* __restrict__ bcur,
                         int* __restrict__ bent){
  int m = blockIdx.x*256 + threadIdx.x;
  if (m >= MPTS) return;
  int2 ii = itab[m];
  int tx0 = ii.x >> 5, tx1 = ((ii.x + 5) % GX) >> 5;
  int ty0 = ii.y >> 5, ty1 = ((ii.y + 5) % GY) >> 5;
  int p = atomicAdd(&bcur[tx0*NTY+ty0],1); bent[p] = m;
  if (tx1!=tx0){ p = atomicAdd(&bcur[tx1*NTY+ty0],1); bent[p] = m; }
  if (ty1!=ty0){
    p = atomicAdd(&bcur[tx0*NTY+ty1],1); bent[p] = m;
    if (tx1!=tx0){ p = atomicAdd(&bcur[tx1*NTY+ty1],1); bent[p] = m; }
  }
}

// ---------- tile gather (table-driven): thread owns 4 cells ----------
template<int BC>
__global__ __launch_bounds__(256) void tile_gather(const float* __restrict__ ydc,
                                                   const float* __restrict__ wtab,
                                                   const int2* __restrict__ itab,
                                                   const int* __restrict__ bstart,
                                                   const int* __restrict__ bend,
                                                   const int* __restrict__ bent,
                                                   bf16* __restrict__ A1, int c0){
  int tile = blockIdx.x;
  int tx = tile / NTY, ty = tile - tx*NTY;
  int x0 = tx*32, y0 = ty*32;
  int t = threadIdx.x;
  int kxl = t >> 3;           // 0..31
  int ky0l = (t & 7) * 4;     // 0,4,..,28
  int kxi  = x0 + kxl;
  int kyi0 = y0 + ky0l;

  __shared__ float swx[CHUNK][6], swy[CHUNK][6];
  __shared__ float sy[CHUNK][2*BC];
  __shared__ int   six0[CHUNK], siy0[CHUNK];

  float accr[4][BC], acci[4][BC];
  #pragma unroll
  for (int q=0;q<4;++q)
    #pragma unroll
    for (int c=0;c<BC;++c){ accr[q][c]=0.f; acci[q][c]=0.f; }

  int beg = bstart[tile], end = bend[tile];
  for (int s0 = beg; s0 < end; s0 += CHUNK){
    int ns = end - s0; if (ns > CHUNK) ns = CHUNK;
    __syncthreads();
    for (int i=t; i<ns; i+=256){
      int m = bent[s0+i];
      const float4* wt = (const float4*)(wtab + (size_t)m*12);
      float4 w0 = wt[0], w1 = wt[1], w2 = wt[2];
      swx[i][0]=w0.x; swx[i][1]=w0.y; swx[i][2]=w0.z; swx[i][3]=w0.w;
      swx[i][4]=w1.x; swx[i][5]=w1.y;
      swy[i][0]=w1.z; swy[i][1]=w1.w; swy[i][2]=w2.x; swy[i][3]=w2.y;
      swy[i][4]=w2.z; swy[i][5]=w2.w;
      int2 ii = itab[m];
      six0[i] = ii.x; siy0[i] = ii.y;
    }
    for (int i=t; i<ns*2*BC; i+=256){
      int s = i / (2*BC), f = i - s*(2*BC);
      sy[s][f] = ydc[((size_t)bent[s0+s]*NC + c0)*2 + f];
    }
    __syncthreads();
    for (int s=0; s<ns; ++s){
      int lx = kxi - six0[s]; if (lx < 0) lx += GX;
      if (lx < 6){
        float wx = swx[s][lx];
        float yr[BC], yi[BC];
        #pragma unroll
        for (int c=0;c<BC;++c){ yr[c] = sy[s][2*c]; yi[c] = sy[s][2*c+1]; }
        int lyb = kyi0 - siy0[s]; if (lyb < 0) lyb += GY;
        #pragma unroll
        for (int q=0;q<4;++q){
          int ly = lyb + q; if (ly >= GY) ly -= GY;
          if (ly < 6){
            float w = wx * swy[s][ly];
            #pragma unroll
            for (int c=0;c<BC;++c){
              accr[q][c] = fmaf(w, yr[c], accr[q][c]);
              acci[q][c] = fmaf(w, yi[c], acci[q][c]);
            }
          }
        }
      }
    }
  }

  float maskq[4];
  #pragma unroll
  for (int q=0;q<4;++q) maskq[q] = ((kyi0 + q) < GY) ? 1.0f : 0.0f;

  #pragma unroll
  for (int c=0;c<BC;++c){
    bf16x4 vr, vi;
    #pragma unroll
    for (int q=0;q<4;++q){
      vr[q] = (bf16)(accr[q][c]*maskq[q]);
      vi[q] = (bf16)(acci[q][c]*maskq[q]);
    }
    size_t base = ((size_t)((c*GX + kxi)*2)) * K1;
    *(bf16x4*)(A1 + base + kyi0)      = vr;
    *(bf16x4*)(A1 + base + K1 + kyi0) = vi;
  }
}

// ---------- twiddle gen (B1 [N1G][K1] and W2t [N2][K2] in one kernel) ----------
#define B1_ELEMS (N1G*K1)
#define W2_ELEMS (N2*K2)
__global__ void gen_tw(bf16* __restrict__ B1, bf16* __restrict__ W2t){
  int i = blockIdx.x*256 + threadIdx.x;
  if (i < B1_ELEMS){
    int nr = i / K1, k = i - nr*K1;
    int n = nr >> 1, p = nr & 1;
    float v = 0.f;
    if (n <= 160 && k < GY){
      int rem = (k * n) % GY;
      float ang = 6.28318530717958647692f * (float)rem / (float)GY;
      float s, c; sincosf(ang, &s, &c);
      v = p ? s : c;
    }
    B1[i] = (bf16)v;
  } else if (i < B1_ELEMS + W2_ELEMS){
    int j = i - B1_ELEMS;
    int n = j / K2, k = j - n*K2;
    float v = 0.f;
    if (n < CROPN){
      int part = k / 1280, kx = k - part*1280;
      int nx = (n < 160) ? (1120 + n) : (n - 160);
      int rem = (kx * nx) % GX;
      float ang = 6.28318530717958647692f * (float)rem / (float)GX;
      float s, c; sincosf(ang, &s, &c);
      v = part ? s : c;
    }
    W2t[j] = (bf16)v;
  }
}

// ---------- pack C1t -> A2, Hermitian reconstruct, contiguous reads ----------
__global__ void pack_A2t(const float* __restrict__ C1t, bf16* __restrict__ A2,
                         int nb, int ldc1){
  int i = blockIdx.x*256 + threadIdx.x;
  if (i >= nb*161*160) return;
  int kxg = i % 160;
  int rem = i / 160;
  int n   = rem % 161;
  int cl  = rem / 161;
  int kx0 = kxg*8;
  int cb  = (cl*GX + kx0)*2;
  const float4* pr = (const float4*)(C1t + (size_t)(2*n)*ldc1 + cb);
  const float4* ps = (const float4*)(C1t + (size_t)(2*n+1)*ldc1 + cb);
  float CR[8], CI[8], SR[8], SI[8];
  #pragma unroll
  for (int j=0;j<4;++j){
    float4 c4 = pr[j], s4 = ps[j];
    CR[2*j] = c4.x; CI[2*j] = c4.y; CR[2*j+1] = c4.z; CI[2*j+1] = c4.w;
    SR[2*j] = s4.x; SI[2*j] = s4.y; SR[2*j+1] = s4.z; SI[2*j+1] = s4.w;
  }
  if (n <= 159){                       // q+ = 160+n
    bf16x8 t0, t1, m1;
    #pragma unroll
    for (int j=0;j<8;++j){
      float a = CR[j] - SI[j];
      float b = SR[j] + CI[j];
      t0[j] = (bf16)a; t1[j] = (bf16)b; m1[j] = (bf16)(-b);
    }
    size_t r0 = ((size_t)(cl*640 + 2*(160+n)))*K2;
    *(bf16x8*)(A2 + r0 + kx0)             = t0;
    *(bf16x8*)(A2 + r0 + 1280 + kx0)      = m1;
    *(bf16x8*)(A2 + r0 + K2 + kx0)        = t1;
    *(bf16x8*)(A2 + r0 + K2 + 1280 + kx0) = t0;
  }
  if (n >= 1){                         // q- = 160-n
    bf16x8 t0, t1, m1;
    #pragma unroll
    for (int j=0;j<8;++j){
      float a = CR[j] + SI[j];
      float b = CI[j] - SR[j];
      t0[j] = (bf16)a; t1[j] = (bf16)b; m1[j] = (bf16)(-b);
    }
    size_t r0 = ((size_t)(cl*640 + 2*(160-n)))*K2;
    *(bf16x8*)(A2 + r0 + kx0)             = t0;
    *(bf16x8*)(A2 + r0 + 1280 + kx0)      = m1;
    *(bf16x8*)(A2 + r0 + K2 + kx0)        = t1;
    *(bf16x8*)(A2 + r0 + K2 + 1280 + kx0) = t0;
  }
}

// ---------- bf16 GEMM, 128x128 tile ----------
#define BM 128
#define BN 128
#define BK 32
#define LDT 40

__global__ __launch_bounds__(256) void gemm_bt(const bf16* __restrict__ A,
                                               const bf16* __restrict__ B,
                                               float* __restrict__ C,
                                               int K, int ldc){
  __shared__ bf16 As[BM*LDT];
  __shared__ bf16 Bs[BM*LDT];
  int t = threadIdx.x;
  int lane = t & 63;
  int wave = t >> 6;
  int wm = wave >> 1, wn = wave & 1;
  size_t tileM = (size_t)blockIdx.x * BM;
  size_t tileN = (size_t)blockIdx.y * BN;

  const bf16* Ab = A + tileM * K;
  const bf16* Bb = B + tileN * K;

  f32x4 zero = {0.f, 0.f, 0.f, 0.f};
  f32x4 acc[4][4];
  #pragma unroll
  for (int m=0;m<4;++m)
    #pragma unroll
    for (int n=0;n<4;++n) acc[m][n] = zero;

  int r0 = t >> 2;
  int kc = (t & 3) * 8;
  size_t aoff = (size_t)r0 * K + kc;

  bf16x8 a0 = *(const bf16x8*)(Ab + aoff);
  bf16x8 a1 = *(const bf16x8*)(Ab + aoff + (size_t)64*K);
  bf16x8 b0 = *(const bf16x8*)(Bb + aoff);
  bf16x8 b1 = *(const bf16x8*)(Bb + aoff + (size_t)64*K);

  int lr = lane & 15, lk = (lane >> 4) * 8;

  for (int kt = 0; kt < K; kt += BK){
    __syncthreads();
    *(bf16x8*)(As + r0*LDT + kc)      = a0;
    *(bf16x8*)(As + (r0+64)*LDT + kc) = a1;
    *(bf16x8*)(Bs + r0*LDT + kc)      = b0;
    *(bf16x8*)(Bs + (r0+64)*LDT + kc) = b1;
    __syncthreads();

    bool more = (kt + BK) < K;
    if (more){
      size_t o = aoff + kt + BK;
      a0 = *(const bf16x8*)(Ab + o);
      a1 = *(const bf16x8*)(Ab + o + (size_t)64*K);
      b0 = *(const bf16x8*)(Bb + o);
      b1 = *(const bf16x8*)(Bb + o + (size_t)64*K);
    }

    bf16x8 af[4], bg[4];
    #pragma unroll
    for (int m=0;m<4;++m)
      af[m] = *(const bf16x8*)(As + (wm*64 + m*16 + lr)*LDT + lk);
    #pragma unroll
    for (int n=0;n<4;++n)
      bg[n] = *(const bf16x8*)(Bs + (wn*64 + n*16 + lr)*LDT + lk);
    #pragma unroll
    for (int m=0;m<4;++m)
      #pragma unroll
      for (int n=0;n<4;++n)
        acc[m][n] = __builtin_amdgcn_mfma_f32_16x16x32_bf16(af[m], bg[n], acc[m][n], 0, 0, 0);
  }

  int lrow = (lane >> 4) * 4;
  #pragma unroll
  for (int m=0;m<4;++m)
    #pragma unroll
    for (int n=0;n<4;++n){
      size_t row = tileM + wm*64 + m*16 + lrow;
      size_t col = tileN + wn*64 + n*16 + lr;
      #pragma unroll
      for (int r=0;r<4;++r)
        C[(row + r)*(size_t)ldc + col] = acc[m][n][r];
    }
}

// ---------- bf16 GEMM, 64x64 tile ----------
__global__ __launch_bounds__(256) void gemm_bt64(const bf16* __restrict__ A,
                                                 const bf16* __restrict__ B,
                                                 float* __restrict__ C,
                                                 int K, int ldc){
  __shared__ bf16 As[64*LDT];
  __shared__ bf16 Bs[64*LDT];
  int t = threadIdx.x;
  int lane = t & 63;
  int wave = t >> 6;
  int wm = wave >> 1, wn = wave & 1;
  size_t tileM = (size_t)blockIdx.x * 64;
  size_t tileN = (size_t)blockIdx.y * 64;

  const bf16* Ab = A + tileM * K;
  const bf16* Bb = B + tileN * K;

  f32x4 zero = {0.f, 0.f, 0.f, 0.f};
  f32x4 acc[2][2];
  #pragma unroll
  for (int m=0;m<2;++m)
    #pragma unroll
    for (int n=0;n<2;++n) acc[m][n] = zero;

  int r0 = t >> 2;
  int kc = (t & 3) * 8;
  size_t aoff = (size_t)r0 * K + kc;

  bf16x8 a0 = *(const bf16x8*)(Ab + aoff);
  bf16x8 b0 = *(const bf16x8*)(Bb + aoff);

  int lr = lane & 15, lk = (lane >> 4) * 8;

  for (int kt = 0; kt < K; kt += BK){
    __syncthreads();
    *(bf16x8*)(As + r0*LDT + kc) = a0;
    *(bf16x8*)(Bs + r0*LDT + kc) = b0;
    __syncthreads();

    bool more = (kt + BK) < K;
    if (more){
      size_t o = aoff + kt + BK;
      a0 = *(const bf16x8*)(Ab + o);
      b0 = *(const bf16x8*)(Bb + o);
    }

    bf16x8 af[2], bg[2];
    #pragma unroll
    for (int m=0;m<2;++m)
      af[m] = *(const bf16x8*)(As + (wm*32 + m*16 + lr)*LDT + lk);
    #pragma unroll
    for (int n=0;n<2;++n)
      bg[n] = *(const bf16x8*)(Bs + (wn*32 + n*16 + lr)*LDT + lk);
    #pragma unroll
    for (int m=0;m<2;++m)
      #pragma unroll
      for (int n=0;n<2;++n)
        acc[m][n] = __builtin_amdgcn_mfma_f32_16x16x32_bf16(af[m], bg[n], acc[m][n], 0, 0, 0);
  }

  int lrow = (lane >> 4) * 4;
  #pragma unroll
  for (int m=0;m<2;++m)
    #pragma unroll
    for (int n=0;n<2;++n){
      size_t row = tileM + wm*32 + m*16 + lrow;
      size_t col = tileN + wn*32 + n*16 + lr;
      #pragma unroll
      for (int r=0;r<4;++r)
        C[(row + r)*(size_t)ldc + col] = acc[m][n][r];
    }
}

// ---------- coil combine (C2t layout: [r][cl*640 + 2q + ri]) ----------
__global__ void combine(const float* __restrict__ C2t,
                        const float* __restrict__ smr, const float* __restrict__ smi,
                        float* __restrict__ accum, int c0, int bc, int ldc2){
  int i = blockIdx.x*256 + threadIdx.x;
  if (i >= CROPN*CROPN) return;
  int r = i / CROPN, q = i - r*CROPN;
  const float* row = C2t + (size_t)r*ldc2;
  float ar = 0.f, ai = 0.f;
  for (int cl=0; cl<bc; ++cl){
    float re = row[cl*640 + 2*q];
    float im = row[cl*640 + 2*q + 1];
    size_t sidx = ((size_t)(c0+cl)*HH + (160+r))*WW + (77+q);
    float sr = smr[sidx], si = smi[sidx];
    ar += sr*re + si*im;
    ai += sr*im - si*re;
  }
  accum[2*i] += ar; accum[2*i+1] += ai;
}

// ---------- deapodization + magnitude ----------
__device__ __forceinline__ float deapod_f(float n, float G){
  float x = 3.14159265358979323846f * 6.0f * n / G;
  float z = 197.1216f - x*x;
  float sz = sqrtf(fabsf(z) + 1e-12f);
  float K;
  if (z > 0.0f){
    float e = __expf(sz);
    K = (e - 1.0f/e)*0.5f/sz;
  } else {
    K = __sinf(sz)/sz;
  }
  return 1.0f/K;
}

__global__ void final_mag(const float* __restrict__ accum, float* __restrict__ out){
  int i = blockIdx.x*256 + threadIdx.x;
  if (i >= CROPN*CROPN) return;
  int r  = i / CROPN;
  int cc = i - r*CROPN;
  float dx = deapod_f((float)(r  - 160), (float)GX);
  float dy = deapod_f((float)(cc - 160), (float)GY);
  float re = accum[2*i], im = accum[2*i+1];
  out[i] = sqrtf(re*re + im*im) * dx * dy;
}

extern "C" void kernel_launch(void* const* d_in, const int* in_sizes, int n_in,
                              void* d_out, int out_size, void* d_ws, size_t ws_size,
                              hipStream_t stream){
  const float* kr    = (const float*)d_in[0];
  const float* ki    = (const float*)d_in[1];
  const float* ktraj = (const float*)d_in[2];
  const float* dc    = (const float*)d_in[3];
  const float* smr   = (const float*)d_in[4];
  const float* smi   = (const float*)d_in[5];
  float* out = (float*)d_out;

  // ---- workspace carve (bytes) ----
  const size_t acc_b   = (size_t)CROPN*CROPN*2*4;
  const size_t B1_b    = (size_t)N1G*K1*2;
  const size_t W2t_b   = (size_t)N2*K2*2;
  const size_t ydc_b   = (size_t)MPTS*NC*2*4;
  const size_t wtab_b  = (size_t)MPTS*12*4;          // 1,966,080
  const size_t itab_b  = (size_t)MPTS*8;             //   327,680
  const size_t bh_b    = 8192;
  const size_t bent_b  = (size_t)MAXENT*4;
  const size_t fixed_b = acc_b+B1_b+W2t_b+ydc_b+wtab_b+itab_b+3*bh_b+bent_b; // ~11.4 MB

  const size_t A1_pc   = (size_t)GX*2*K1*2;          // 4,915,200 (A2 aliases A1)
  const size_t C1_pc   = (size_t)GX*2*N1G*4;         // 3,932,160
  const size_t C2_pc   = (size_t)640*N2*4;           //   983,040
  const size_t percoil = A1_pc + C1_pc + C2_pc;

  int bc = 1;
  if (ws_size > fixed_b + percoil){
    size_t b = (ws_size - fixed_b) / percoil;
    bc = (int)(b > 8 ? 8 : b);
    if (bc < 1) bc = 1;
  }

  char* p = (char*)d_ws;
  float* accum  = (float*)p; p += acc_b;
  bf16*  B1     = (bf16*)p;  p += B1_b;
  bf16*  W2t    = (bf16*)p;  p += W2t_b;
  float* ydc    = (float*)p; p += ydc_b;
  float* wtab   = (float*)p; p += wtab_b;
  int2*  itab   = (int2*)p;  p += itab_b;
  int*   bhist  = (int*)p;   p += bh_b;
  int*   bstart = (int*)p;   p += bh_b;
  int*   bcur   = (int*)p;   p += bh_b;
  int*   bent   = (int*)p;   p += bent_b;
  bf16*  A1     = (bf16*)p;
  bf16*  A2     = (bf16*)p;  p += (size_t)bc*A1_pc;   // A2 aliases A1 (dead after GEMM1)
  float* C1t    = (float*)p; p += (size_t)bc*C1_pc;
  float* C2t    = (float*)p; p += (size_t)bc*C2_pc;

  // ---- one-time builds ----
  hipMemsetAsync(bhist, 0, NTILE*4, stream);
  prep<<<(MPTS+255)/256, 256, 0, stream>>>(kr, ki, dc, ktraj, ydc, wtab, itab, bhist);
  bin_scan<<<1, 256, 0, stream>>>(bhist, bstart, bcur);
  bin_fill<<<(MPTS+255)/256, 256, 0, stream>>>(itab, bcur, bent);
  gen_tw<<<(B1_ELEMS+W2_ELEMS+255)/256, 256, 0, stream>>>(B1, W2t);
  hipMemsetAsync(accum, 0, acc_b, stream);

  // ---- per coil-batch pipeline ----
  for (int c0 = 0; c0 < NC; c0 += bc){
    int nb = NC - c0; if (nb > bc) nb = bc;

    switch (nb){
      case 1: tile_gather<1><<<NTILE,256,0,stream>>>(ydc,wtab,itab,bstart,bcur,bent,A1,c0); break;
      case 2: tile_gather<2><<<NTILE,256,0,stream>>>(ydc,wtab,itab,bstart,bcur,bent,A1,c0); break;
      case 3: tile_gather<3><<<NTILE,256,0,stream>>>(ydc,wtab,itab,bstart,bcur,bent,A1,c0); break;
      case 4: tile_gather<4><<<NTILE,256,0,stream>>>(ydc,wtab,itab,bstart,bcur,bent,A1,c0); break;
      case 5: tile_gather<5><<<NTILE,256,0,stream>>>(ydc,wtab,itab,bstart,bcur,bent,A1,c0); break;
      case 6: tile_gather<6><<<NTILE,256,0,stream>>>(ydc,wtab,itab,bstart,bcur,bent,A1,c0); break;
      case 7: tile_gather<7><<<NTILE,256,0,stream>>>(ydc,wtab,itab,bstart,bcur,bent,A1,c0); break;
      default: tile_gather<8><<<NTILE,256,0,stream>>>(ydc,wtab,itab,bstart,bcur,bent,A1,c0); break;
    }

    // GEMM1 (operands swapped): C1t[384][nb*2560] = B1 x A1^T
    gemm_bt<<<dim3(N1G/BM, nb*(GX*2/BN)), 256, 0, stream>>>(B1, A1, C1t, K1, nb*2560);

    int tot2 = nb*161*160;
    pack_A2t<<<(tot2+255)/256, 256, 0, stream>>>(C1t, A2, nb, nb*2560);

    // GEMM2 (operands swapped, 64x64 tiles, 320 used rows = 5 M-tiles)
    gemm_bt64<<<dim3(5, nb*10), 256, 0, stream>>>(W2t, A2, C2t, K2, nb*640);

    combine<<<(CROPN*CROPN+255)/256, 256, 0, stream>>>(C2t, smr, smi, accum, c0, nb, nb*640);
  }
  final_mag<<<(CROPN*CROPN+255)/256, 256, 0, stream>>>(accum, out);
}

// Round 8
// 220.322 us; speedup vs baseline: 3.3166x; 1.2200x over previous
//
#include <hip/hip_runtime.h>

typedef __bf16 bf16;
typedef __attribute__((ext_vector_type(8))) __bf16 bf16x8;
typedef __attribute__((ext_vector_type(4))) __bf16 bf16x4;
typedef __attribute__((ext_vector_type(4))) float f32x4;

#define MPTS 40960
#define NC 15
#define GX 1280
#define GY 948
#define HH 640
#define WW 474
#define CROPN 320

#define K1 960    // ky padded 948->960, real input
#define N1G 384   // rows 2n+p, n<=160 used (322), padded to 384
#define K2 2560   // [tr(1280 kx) | ti(1280)]
#define N2 384    // 320 image rows padded to 384 (only 320 computed)

#define NTX 40
#define NTY 30
#define NTILE (NTX*NTY)   // 1200
#define MAXENT (MPTS*4)
#define CHUNK 128

// ---------- modified Bessel I0 (A&S 9.8.1 / 9.8.2) ----------
__device__ __forceinline__ float i0f_dev(float x){
  if (x < 3.75f){
    float t = x*(1.0f/3.75f); t *= t;
    return 1.0f + t*(3.5156229f + t*(3.0899424f + t*(1.2067492f +
                 t*(0.2659732f + t*(0.0360768f + t*0.0045813f)))));
  } else {
    float t = 3.75f/x;
    float p = 0.39894228f + t*(0.01328592f + t*(0.00225319f + t*(-0.00157565f +
              t*(0.00916281f + t*(-0.02057706f + t*(0.02635537f +
              t*(-0.01647633f + t*0.00392377f)))))));
    return __expf(x)*rsqrtf(x)*p;
  }
}

__device__ __forceinline__ float kb_w(float u){
  float a = 1.0f - u*u*(1.0f/9.0f);
  return i0f_dev(14.04f*sqrtf(fmaxf(a, 0.0f)))*(1.0f/6.0f);
}

// ---------- prep: ydc = kspace*dcomp, KB tap tables, tile histogram ----------
__global__ void prep(const float* __restrict__ kr, const float* __restrict__ ki,
                     const float* __restrict__ dc, const float* __restrict__ ktraj,
                     float* __restrict__ ydc, float* __restrict__ wtab,
                     int2* __restrict__ itab, int* __restrict__ bhist){
  int m = blockIdx.x*256 + threadIdx.x;
  if (m >= MPTS) return;
  float d = dc[m];
  #pragma unroll
  for (int c=0;c<NC;++c){
    ydc[((size_t)m*NC + c)*2    ] = kr[(size_t)c*MPTS + m]*d;
    ydc[((size_t)m*NC + c)*2 + 1] = ki[(size_t)c*MPTS + m]*d;
  }
  const float PI2 = 6.28318530717958647692f;
  float tmx = ktraj[m]        * ((float)GX/PI2);
  float tmy = ktraj[MPTS + m] * ((float)GY/PI2);
  float bx = floorf(tmx - 3.0f), by = floorf(tmy - 3.0f);
  float wx[6], wy[6];
  #pragma unroll
  for (int j=0;j<6;++j){
    wx[j] = kb_w(tmx - (bx + (float)(j+1)));
    wy[j] = kb_w(tmy - (by + (float)(j+1)));
  }
  float4* wt = (float4*)(wtab + (size_t)m*12);
  wt[0] = make_float4(wx[0], wx[1], wx[2], wx[3]);
  wt[1] = make_float4(wx[4], wx[5], wy[0], wy[1]);
  wt[2] = make_float4(wy[2], wy[3], wy[4], wy[5]);
  int ix0 = ((int)bx + 1) % GX; if (ix0 < 0) ix0 += GX;
  int iy0 = ((int)by + 1) % GY; if (iy0 < 0) iy0 += GY;
  itab[m] = make_int2(ix0, iy0);
  int tx0 = ix0 >> 5, tx1 = ((ix0 + 5) % GX) >> 5;
  int ty0 = iy0 >> 5, ty1 = ((iy0 + 5) % GY) >> 5;
  atomicAdd(&bhist[tx0*NTY+ty0],1);
  if (tx1!=tx0) atomicAdd(&bhist[tx1*NTY+ty0],1);
  if (ty1!=ty0){
    atomicAdd(&bhist[tx0*NTY+ty1],1);
    if (tx1!=tx0) atomicAdd(&bhist[tx1*NTY+ty1],1);
  }
}

__global__ __launch_bounds__(256) void bin_scan(const int* __restrict__ bhist,
                                                int* __restrict__ bstart,
                                                int* __restrict__ bcur){
  __shared__ int ps[256];
  int t = threadIdx.x;
  int v[5]; int s = 0;
  #pragma unroll
  for (int j=0;j<5;++j){ int i = t*5+j; v[j] = (i<NTILE)?bhist[i]:0; s += v[j]; }
  ps[t] = s; __syncthreads();
  for (int off=1; off<256; off<<=1){
    int x = (t>=off) ? ps[t-off] : 0;
    __syncthreads();
    ps[t] += x;
    __syncthreads();
  }
  int run = (t==0) ? 0 : ps[t-1];
  #pragma unroll
  for (int j=0;j<5;++j){
    int i = t*5+j;
    if (i<NTILE){ bstart[i]=run; bcur[i]=run; }
    run += v[j];
  }
}

__global__ void bin_fill(const int2* __restrict__ itab, int* __restrict__ bcur,
                         int* __restrict__ bent){
  int m = blockIdx.x*256 + threadIdx.x;
  if (m >= MPTS) return;
  int2 ii = itab[m];
  int tx0 = ii.x >> 5, tx1 = ((ii.x + 5) % GX) >> 5;
  int ty0 = ii.y >> 5, ty1 = ((ii.y + 5) % GY) >> 5;
  int p = atomicAdd(&bcur[tx0*NTY+ty0],1); bent[p] = m;
  if (tx1!=tx0){ p = atomicAdd(&bcur[tx1*NTY+ty0],1); bent[p] = m; }
  if (ty1!=ty0){
    p = atomicAdd(&bcur[tx0*NTY+ty1],1); bent[p] = m;
    if (tx1!=tx0){ p = atomicAdd(&bcur[tx1*NTY+ty1],1); bent[p] = m; }
  }
}

// ---------- tile gather (table-driven): thread owns 4 cells, all BC coils ----------
template<int BC>
__global__ __launch_bounds__(256) void tile_gather(const float* __restrict__ ydc,
                                                   const float* __restrict__ wtab,
                                                   const int2* __restrict__ itab,
                                                   const int* __restrict__ bstart,
                                                   const int* __restrict__ bend,
                                                   const int* __restrict__ bent,
                                                   bf16* __restrict__ A1, int c0){
  int tile = blockIdx.x;
  int tx = tile / NTY, ty = tile - tx*NTY;
  int x0 = tx*32, y0 = ty*32;
  int t = threadIdx.x;
  int kxl = t >> 3;           // 0..31
  int ky0l = (t & 7) * 4;     // 0,4,..,28
  int kxi  = x0 + kxl;
  int kyi0 = y0 + ky0l;

  __shared__ float swx[CHUNK][6], swy[CHUNK][6];
  __shared__ float sy[CHUNK][2*BC];
  __shared__ int   six0[CHUNK], siy0[CHUNK];

  float accr[4][BC], acci[4][BC];
  #pragma unroll
  for (int q=0;q<4;++q)
    #pragma unroll
    for (int c=0;c<BC;++c){ accr[q][c]=0.f; acci[q][c]=0.f; }

  int beg = bstart[tile], end = bend[tile];
  for (int s0 = beg; s0 < end; s0 += CHUNK){
    int ns = end - s0; if (ns > CHUNK) ns = CHUNK;
    __syncthreads();
    for (int i=t; i<ns; i+=256){
      int m = bent[s0+i];
      const float4* wt = (const float4*)(wtab + (size_t)m*12);
      float4 w0 = wt[0], w1 = wt[1], w2 = wt[2];
      swx[i][0]=w0.x; swx[i][1]=w0.y; swx[i][2]=w0.z; swx[i][3]=w0.w;
      swx[i][4]=w1.x; swx[i][5]=w1.y;
      swy[i][0]=w1.z; swy[i][1]=w1.w; swy[i][2]=w2.x; swy[i][3]=w2.y;
      swy[i][4]=w2.z; swy[i][5]=w2.w;
      int2 ii = itab[m];
      six0[i] = ii.x; siy0[i] = ii.y;
    }
    for (int i=t; i<ns*2*BC; i+=256){
      int s = i / (2*BC), f = i - s*(2*BC);
      sy[s][f] = ydc[((size_t)bent[s0+s]*NC + c0)*2 + f];
    }
    __syncthreads();
    for (int s=0; s<ns; ++s){
      int lx = kxi - six0[s]; if (lx < 0) lx += GX;
      if (lx < 6){
        float wx = swx[s][lx];
        int lyb = kyi0 - siy0[s]; if (lyb < 0) lyb += GY;
        // per-cell weights, no branches (cndmask)
        float wq[4];
        #pragma unroll
        for (int q=0;q<4;++q){
          int ly = lyb + q; if (ly >= GY) ly -= GY;
          wq[q] = (ly < 6) ? wx * swy[s][ly] : 0.0f;
        }
        #pragma unroll
        for (int c=0;c<BC;++c){
          float yrc = sy[s][2*c], yic = sy[s][2*c+1];
          #pragma unroll
          for (int q=0;q<4;++q){
            accr[q][c] = fmaf(wq[q], yrc, accr[q][c]);
            acci[q][c] = fmaf(wq[q], yic, acci[q][c]);
          }
        }
      }
    }
  }

  float maskq[4];
  #pragma unroll
  for (int q=0;q<4;++q) maskq[q] = ((kyi0 + q) < GY) ? 1.0f : 0.0f;

  #pragma unroll
  for (int c=0;c<BC;++c){
    bf16x4 vr, vi;
    #pragma unroll
    for (int q=0;q<4;++q){
      vr[q] = (bf16)(accr[q][c]*maskq[q]);
      vi[q] = (bf16)(acci[q][c]*maskq[q]);
    }
    size_t base = ((size_t)((c*GX + kxi)*2)) * K1;
    *(bf16x4*)(A1 + base + kyi0)      = vr;
    *(bf16x4*)(A1 + base + K1 + kyi0) = vi;
  }
}

// ---------- twiddle gen ----------
#define B1_ELEMS (N1G*K1)
#define W2_ELEMS (N2*K2)
__global__ void gen_tw(bf16* __restrict__ B1, bf16* __restrict__ W2t){
  int i = blockIdx.x*256 + threadIdx.x;
  if (i < B1_ELEMS){
    int nr = i / K1, k = i - nr*K1;
    int n = nr >> 1, p = nr & 1;
    float v = 0.f;
    if (n <= 160 && k < GY){
      int rem = (k * n) % GY;
      float ang = 6.28318530717958647692f * (float)rem / (float)GY;
      float s, c; sincosf(ang, &s, &c);
      v = p ? s : c;
    }
    B1[i] = (bf16)v;
  } else if (i < B1_ELEMS + W2_ELEMS){
    int j = i - B1_ELEMS;
    int n = j / K2, k = j - n*K2;
    float v = 0.f;
    if (n < CROPN){
      int part = k / 1280, kx = k - part*1280;
      int nx = (n < 160) ? (1120 + n) : (n - 160);
      int rem = (kx * nx) % GX;
      float ang = 6.28318530717958647692f * (float)rem / (float)GX;
      float s, c; sincosf(ang, &s, &c);
      v = part ? s : c;
    }
    W2t[j] = (bf16)v;
  }
}

// ---------- pack C1t(bf16) -> A2, Hermitian reconstruct ----------
__global__ void pack_A2t(const bf16* __restrict__ C1t, bf16* __restrict__ A2,
                         int nb, int ldc1){
  int i = blockIdx.x*256 + threadIdx.x;
  if (i >= nb*161*160) return;
  int kxg = i % 160;
  int rem = i / 160;
  int n   = rem % 161;
  int cl  = rem / 161;
  int kx0 = kxg*8;
  int cb  = (cl*GX + kx0)*2;
  const bf16x8* pr = (const bf16x8*)(C1t + (size_t)(2*n)*ldc1 + cb);
  const bf16x8* ps = (const bf16x8*)(C1t + (size_t)(2*n+1)*ldc1 + cb);
  float CR[8], CI[8], SR[8], SI[8];
  #pragma unroll
  for (int h=0;h<2;++h){
    bf16x8 c8 = pr[h], s8 = ps[h];
    #pragma unroll
    for (int j=0;j<4;++j){
      CR[h*4+j] = (float)c8[2*j]; CI[h*4+j] = (float)c8[2*j+1];
      SR[h*4+j] = (float)s8[2*j]; SI[h*4+j] = (float)s8[2*j+1];
    }
  }
  // NOTE: order above walks kx in pairs: elements h*4+j correspond to kx0+h*4+j? No:
  // c8[2*j],c8[2*j+1] are (gr,gi) of kx0 + h*4 + j. Layout matches previous float4 path.
  if (n <= 159){                       // q+ = 160+n
    bf16x8 t0, t1, m1;
    #pragma unroll
    for (int j=0;j<8;++j){
      float a = CR[j] - SI[j];
      float b = SR[j] + CI[j];
      t0[j] = (bf16)a; t1[j] = (bf16)b; m1[j] = (bf16)(-b);
    }
    size_t r0 = ((size_t)(cl*640 + 2*(160+n)))*K2;
    *(bf16x8*)(A2 + r0 + kx0)             = t0;
    *(bf16x8*)(A2 + r0 + 1280 + kx0)      = m1;
    *(bf16x8*)(A2 + r0 + K2 + kx0)        = t1;
    *(bf16x8*)(A2 + r0 + K2 + 1280 + kx0) = t0;
  }
  if (n >= 1){                         // q- = 160-n
    bf16x8 t0, t1, m1;
    #pragma unroll
    for (int j=0;j<8;++j){
      float a = CR[j] + SI[j];
      float b = CI[j] - SR[j];
      t0[j] = (bf16)a; t1[j] = (bf16)b; m1[j] = (bf16)(-b);
    }
    size_t r0 = ((size_t)(cl*640 + 2*(160-n)))*K2;
    *(bf16x8*)(A2 + r0 + kx0)             = t0;
    *(bf16x8*)(A2 + r0 + 1280 + kx0)      = m1;
    *(bf16x8*)(A2 + r0 + K2 + kx0)        = t1;
    *(bf16x8*)(A2 + r0 + K2 + 1280 + kx0) = t0;
  }
}

// ---------- bf16 GEMM, 128x128 tile, bf16 C output ----------
#define BM 128
#define BN 128
#define BK 32
#define LDT 40

__global__ __launch_bounds__(256) void gemm_bt(const bf16* __restrict__ A,
                                               const bf16* __restrict__ B,
                                               bf16* __restrict__ C,
                                               int K, int ldc){
  __shared__ bf16 As[BM*LDT];
  __shared__ bf16 Bs[BM*LDT];
  int t = threadIdx.x;
  int lane = t & 63;
  int wave = t >> 6;
  int wm = wave >> 1, wn = wave & 1;
  size_t tileM = (size_t)blockIdx.x * BM;
  size_t tileN = (size_t)blockIdx.y * BN;

  const bf16* Ab = A + tileM * K;
  const bf16* Bb = B + tileN * K;

  f32x4 zero = {0.f, 0.f, 0.f, 0.f};
  f32x4 acc[4][4];
  #pragma unroll
  for (int m=0;m<4;++m)
    #pragma unroll
    for (int n=0;n<4;++n) acc[m][n] = zero;

  int r0 = t >> 2;
  int kc = (t & 3) * 8;
  size_t aoff = (size_t)r0 * K + kc;

  bf16x8 a0 = *(const bf16x8*)(Ab + aoff);
  bf16x8 a1 = *(const bf16x8*)(Ab + aoff + (size_t)64*K);
  bf16x8 b0 = *(const bf16x8*)(Bb + aoff);
  bf16x8 b1 = *(const bf16x8*)(Bb + aoff + (size_t)64*K);

  int lr = lane & 15, lk = (lane >> 4) * 8;

  for (int kt = 0; kt < K; kt += BK){
    __syncthreads();
    *(bf16x8*)(As + r0*LDT + kc)      = a0;
    *(bf16x8*)(As + (r0+64)*LDT + kc) = a1;
    *(bf16x8*)(Bs + r0*LDT + kc)      = b0;
    *(bf16x8*)(Bs + (r0+64)*LDT + kc) = b1;
    __syncthreads();

    bool more = (kt + BK) < K;
    if (more){
      size_t o = aoff + kt + BK;
      a0 = *(const bf16x8*)(Ab + o);
      a1 = *(const bf16x8*)(Ab + o + (size_t)64*K);
      b0 = *(const bf16x8*)(Bb + o);
      b1 = *(const bf16x8*)(Bb + o + (size_t)64*K);
    }

    bf16x8 af[4], bg[4];
    #pragma unroll
    for (int m=0;m<4;++m)
      af[m] = *(const bf16x8*)(As + (wm*64 + m*16 + lr)*LDT + lk);
    #pragma unroll
    for (int n=0;n<4;++n)
      bg[n] = *(const bf16x8*)(Bs + (wn*64 + n*16 + lr)*LDT + lk);
    #pragma unroll
    for (int m=0;m<4;++m)
      #pragma unroll
      for (int n=0;n<4;++n)
        acc[m][n] = __builtin_amdgcn_mfma_f32_16x16x32_bf16(af[m], bg[n], acc[m][n], 0, 0, 0);
  }

  int lrow = (lane >> 4) * 4;
  #pragma unroll
  for (int m=0;m<4;++m)
    #pragma unroll
    for (int n=0;n<4;++n){
      size_t row = tileM + wm*64 + m*16 + lrow;
      size_t col = tileN + wn*64 + n*16 + lr;
      #pragma unroll
      for (int r=0;r<4;++r)
        C[(row + r)*(size_t)ldc + col] = (bf16)acc[m][n][r];
    }
}

// ---------- bf16 GEMM, 64x64 tile, fp32 C ----------
__global__ __launch_bounds__(256) void gemm_bt64(const bf16* __restrict__ A,
                                                 const bf16* __restrict__ B,
                                                 float* __restrict__ C,
                                                 int K, int ldc){
  __shared__ bf16 As[64*LDT];
  __shared__ bf16 Bs[64*LDT];
  int t = threadIdx.x;
  int lane = t & 63;
  int wave = t >> 6;
  int wm = wave >> 1, wn = wave & 1;
  size_t tileM = (size_t)blockIdx.x * 64;
  size_t tileN = (size_t)blockIdx.y * 64;

  const bf16* Ab = A + tileM * K;
  const bf16* Bb = B + tileN * K;

  f32x4 zero = {0.f, 0.f, 0.f, 0.f};
  f32x4 acc[2][2];
  #pragma unroll
  for (int m=0;m<2;++m)
    #pragma unroll
    for (int n=0;n<2;++n) acc[m][n] = zero;

  int r0 = t >> 2;
  int kc = (t & 3) * 8;
  size_t aoff = (size_t)r0 * K + kc;

  bf16x8 a0 = *(const bf16x8*)(Ab + aoff);
  bf16x8 b0 = *(const bf16x8*)(Bb + aoff);

  int lr = lane & 15, lk = (lane >> 4) * 8;

  for (int kt = 0; kt < K; kt += BK){
    __syncthreads();
    *(bf16x8*)(As + r0*LDT + kc) = a0;
    *(bf16x8*)(Bs + r0*LDT + kc) = b0;
    __syncthreads();

    bool more = (kt + BK) < K;
    if (more){
      size_t o = aoff + kt + BK;
      a0 = *(const bf16x8*)(Ab + o);
      b0 = *(const bf16x8*)(Bb + o);
    }

    bf16x8 af[2], bg[2];
    #pragma unroll
    for (int m=0;m<2;++m)
      af[m] = *(const bf16x8*)(As + (wm*32 + m*16 + lr)*LDT + lk);
    #pragma unroll
    for (int n=0;n<2;++n)
      bg[n] = *(const bf16x8*)(Bs + (wn*32 + n*16 + lr)*LDT + lk);
    #pragma unroll
    for (int m=0;m<2;++m)
      #pragma unroll
      for (int n=0;n<2;++n)
        acc[m][n] = __builtin_amdgcn_mfma_f32_16x16x32_bf16(af[m], bg[n], acc[m][n], 0, 0, 0);
  }

  int lrow = (lane >> 4) * 4;
  #pragma unroll
  for (int m=0;m<2;++m)
    #pragma unroll
    for (int n=0;n<2;++n){
      size_t row = tileM + wm*32 + m*16 + lrow;
      size_t col = tileN + wn*32 + n*16 + lr;
      #pragma unroll
      for (int r=0;r<4;++r)
        C[(row + r)*(size_t)ldc + col] = acc[m][n][r];
    }
}

// ---------- coil combine (C2t layout: [r][cl*640 + 2q + ri]) ----------
__global__ void combine(const float* __restrict__ C2t,
                        const float* __restrict__ smr, const float* __restrict__ smi,
                        float* __restrict__ accum, int c0, int bc, int ldc2){
  int i = blockIdx.x*256 + threadIdx.x;
  if (i >= CROPN*CROPN) return;
  int r = i / CROPN, q = i - r*CROPN;
  const float* row = C2t + (size_t)r*ldc2;
  float ar = 0.f, ai = 0.f;
  for (int cl=0; cl<bc; ++cl){
    float re = row[cl*640 + 2*q];
    float im = row[cl*640 + 2*q + 1];
    size_t sidx = ((size_t)(c0+cl)*HH + (160+r))*WW + (77+q);
    float sr = smr[sidx], si = smi[sidx];
    ar += sr*re + si*im;
    ai += sr*im - si*re;
  }
  accum[2*i] += ar; accum[2*i+1] += ai;
}

// ---------- deapodization + magnitude ----------
__device__ __forceinline__ float deapod_f(float n, float G){
  float x = 3.14159265358979323846f * 6.0f * n / G;
  float z = 197.1216f - x*x;
  float sz = sqrtf(fabsf(z) + 1e-12f);
  float K;
  if (z > 0.0f){
    float e = __expf(sz);
    K = (e - 1.0f/e)*0.5f/sz;
  } else {
    K = __sinf(sz)/sz;
  }
  return 1.0f/K;
}

__global__ void final_mag(const float* __restrict__ accum, float* __restrict__ out){
  int i = blockIdx.x*256 + threadIdx.x;
  if (i >= CROPN*CROPN) return;
  int r  = i / CROPN;
  int cc = i - r*CROPN;
  float dx = deapod_f((float)(r  - 160), (float)GX);
  float dy = deapod_f((float)(cc - 160), (float)GY);
  float re = accum[2*i], im = accum[2*i+1];
  out[i] = sqrtf(re*re + im*im) * dx * dy;
}

// tile_gather dispatch helper
static void launch_gather(int nb, const float* ydc, const float* wtab, const int2* itab,
                          const int* bstart, const int* bcur, const int* bent,
                          bf16* A1, int c0, hipStream_t stream){
  switch (nb){
    case 1:  tile_gather<1><<<NTILE,256,0,stream>>>(ydc,wtab,itab,bstart,bcur,bent,A1,c0); break;
    case 2:  tile_gather<2><<<NTILE,256,0,stream>>>(ydc,wtab,itab,bstart,bcur,bent,A1,c0); break;
    case 3:  tile_gather<3><<<NTILE,256,0,stream>>>(ydc,wtab,itab,bstart,bcur,bent,A1,c0); break;
    case 4:  tile_gather<4><<<NTILE,256,0,stream>>>(ydc,wtab,itab,bstart,bcur,bent,A1,c0); break;
    case 5:  tile_gather<5><<<NTILE,256,0,stream>>>(ydc,wtab,itab,bstart,bcur,bent,A1,c0); break;
    case 6:  tile_gather<6><<<NTILE,256,0,stream>>>(ydc,wtab,itab,bstart,bcur,bent,A1,c0); break;
    case 7:  tile_gather<7><<<NTILE,256,0,stream>>>(ydc,wtab,itab,bstart,bcur,bent,A1,c0); break;
    case 8:  tile_gather<8><<<NTILE,256,0,stream>>>(ydc,wtab,itab,bstart,bcur,bent,A1,c0); break;
    case 9:  tile_gather<9><<<NTILE,256,0,stream>>>(ydc,wtab,itab,bstart,bcur,bent,A1,c0); break;
    case 10: tile_gather<10><<<NTILE,256,0,stream>>>(ydc,wtab,itab,bstart,bcur,bent,A1,c0); break;
    case 11: tile_gather<11><<<NTILE,256,0,stream>>>(ydc,wtab,itab,bstart,bcur,bent,A1,c0); break;
    case 12: tile_gather<12><<<NTILE,256,0,stream>>>(ydc,wtab,itab,bstart,bcur,bent,A1,c0); break;
    case 13: tile_gather<13><<<NTILE,256,0,stream>>>(ydc,wtab,itab,bstart,bcur,bent,A1,c0); break;
    case 14: tile_gather<14><<<NTILE,256,0,stream>>>(ydc,wtab,itab,bstart,bcur,bent,A1,c0); break;
    default: tile_gather<15><<<NTILE,256,0,stream>>>(ydc,wtab,itab,bstart,bcur,bent,A1,c0); break;
  }
}

extern "C" void kernel_launch(void* const* d_in, const int* in_sizes, int n_in,
                              void* d_out, int out_size, void* d_ws, size_t ws_size,
                              hipStream_t stream){
  const float* kr    = (const float*)d_in[0];
  const float* ki    = (const float*)d_in[1];
  const float* ktraj = (const float*)d_in[2];
  const float* dc    = (const float*)d_in[3];
  const float* smr   = (const float*)d_in[4];
  const float* smi   = (const float*)d_in[5];
  float* out = (float*)d_out;

  // ---- workspace carve (bytes) ----
  const size_t acc_b   = (size_t)CROPN*CROPN*2*4;
  const size_t B1_b    = (size_t)N1G*K1*2;
  const size_t W2t_b   = (size_t)N2*K2*2;
  const size_t ydc_b   = (size_t)MPTS*NC*2*4;
  const size_t wtab_b  = (size_t)MPTS*12*4;
  const size_t itab_b  = (size_t)MPTS*8;
  const size_t bh_b    = 8192;
  const size_t bent_b  = (size_t)MAXENT*4;
  const size_t fixed_b = acc_b+B1_b+W2t_b+ydc_b+wtab_b+itab_b+3*bh_b+bent_b; // ~11.4 MB

  const size_t A1_pc   = (size_t)GX*2*K1*2;          // 4,915,200 (A2 aliases A1)
  const size_t C1_pc   = (size_t)GX*2*N1G*2;         // 1,966,080 (bf16 now)
  const size_t C2_pc   = (size_t)640*N2*4;           //   983,040
  const size_t percoil = A1_pc + C1_pc + C2_pc;      // 7,864,320

  int bc = 1;
  if (ws_size > fixed_b + percoil){
    size_t b = (ws_size - fixed_b) / percoil;
    bc = (int)(b > NC ? NC : b);
    if (bc < 1) bc = 1;
  }

  char* p = (char*)d_ws;
  float* accum  = (float*)p; p += acc_b;
  bf16*  B1     = (bf16*)p;  p += B1_b;
  bf16*  W2t    = (bf16*)p;  p += W2t_b;
  float* ydc    = (float*)p; p += ydc_b;
  float* wtab   = (float*)p; p += wtab_b;
  int2*  itab   = (int2*)p;  p += itab_b;
  int*   bhist  = (int*)p;   p += bh_b;
  int*   bstart = (int*)p;   p += bh_b;
  int*   bcur   = (int*)p;   p += bh_b;
  int*   bent   = (int*)p;   p += bent_b;
  bf16*  A1     = (bf16*)p;
  bf16*  A2     = (bf16*)p;  p += (size_t)bc*A1_pc;   // A2 aliases A1 (dead after GEMM1)
  bf16*  C1t    = (bf16*)p;  p += (size_t)bc*C1_pc;
  float* C2t    = (float*)p; p += (size_t)bc*C2_pc;

  // ---- one-time builds ----
  hipMemsetAsync(bhist, 0, NTILE*4, stream);
  prep<<<(MPTS+255)/256, 256, 0, stream>>>(kr, ki, dc, ktraj, ydc, wtab, itab, bhist);
  bin_scan<<<1, 256, 0, stream>>>(bhist, bstart, bcur);
  bin_fill<<<(MPTS+255)/256, 256, 0, stream>>>(itab, bcur, bent);
  gen_tw<<<(B1_ELEMS+W2_ELEMS+255)/256, 256, 0, stream>>>(B1, W2t);
  hipMemsetAsync(accum, 0, acc_b, stream);

  // ---- per coil-batch pipeline (single batch when bc==15) ----
  for (int c0 = 0; c0 < NC; c0 += bc){
    int nb = NC - c0; if (nb > bc) nb = bc;

    launch_gather(nb, ydc, wtab, itab, bstart, bcur, bent, A1, c0, stream);

    // GEMM1 (operands swapped): C1t[384][nb*2560] = B1 x A1^T (bf16 out)
    gemm_bt<<<dim3(N1G/BM, nb*(GX*2/BN)), 256, 0, stream>>>(B1, A1, C1t, K1, nb*2560);

    int tot2 = nb*161*160;
    pack_A2t<<<(tot2+255)/256, 256, 0, stream>>>(C1t, A2, nb, nb*2560);

    // GEMM2 (operands swapped, 64x64 tiles, 320 used rows = 5 M-tiles)
    gemm_bt64<<<dim3(5, nb*10), 256, 0, stream>>>(W2t, A2, C2t, K2, nb*640);

    combine<<<(CROPN*CROPN+255)/256, 256, 0, stream>>>(C2t, smr, smi, accum, c0, nb, nb*640);
  }
  final_mag<<<(CROPN*CROPN+255)/256, 256, 0, stream>>>(accum, out);
}

// Round 9
// 204.229 us; speedup vs baseline: 3.5779x; 1.0788x over previous
//
#include <hip/hip_runtime.h>

typedef __bf16 bf16;
typedef __attribute__((ext_vector_type(8))) __bf16 bf16x8;
typedef __attribute__((ext_vector_type(4))) __bf16 bf16x4;
typedef __attribute__((ext_vector_type(4))) float f32x4;

#define MPTS 40960
#define NC 15
#define GX 1280
#define GY 948
#define HH 640
#define WW 474
#define CROPN 320

#define K1 960    // ky padded 948->960, real input
#define M1 384    // twiddle rows 2n+p, n<=160 used (322), padded to 384
#define K2 1280   // kx
#define M2 640    // W2 rows 2r+b, r<320

#define NTX 40
#define NTY 30
#define NTILE (NTX*NTY)   // 1200
#define MAXENT (MPTS*4)
#define CHUNK 128

// ---------- modified Bessel I0 (A&S 9.8.1 / 9.8.2) ----------
__device__ __forceinline__ float i0f_dev(float x){
  if (x < 3.75f){
    float t = x*(1.0f/3.75f); t *= t;
    return 1.0f + t*(3.5156229f + t*(3.0899424f + t*(1.2067492f +
                 t*(0.2659732f + t*(0.0360768f + t*0.0045813f)))));
  } else {
    float t = 3.75f/x;
    float p = 0.39894228f + t*(0.01328592f + t*(0.00225319f + t*(-0.00157565f +
              t*(0.00916281f + t*(-0.02057706f + t*(0.02635537f +
              t*(-0.01647633f + t*0.00392377f)))))));
    return __expf(x)*rsqrtf(x)*p;
  }
}

__device__ __forceinline__ float kb_w(float u){
  float a = 1.0f - u*u*(1.0f/9.0f);
  return i0f_dev(14.04f*sqrtf(fmaxf(a, 0.0f)))*(1.0f/6.0f);
}

// ---------- prep: ydc = kspace*dcomp, KB tap tables, tile histogram ----------
__global__ void prep(const float* __restrict__ kr, const float* __restrict__ ki,
                     const float* __restrict__ dc, const float* __restrict__ ktraj,
                     float* __restrict__ ydc, float* __restrict__ wtab,
                     int2* __restrict__ itab, int* __restrict__ bhist){
  int m = blockIdx.x*256 + threadIdx.x;
  if (m >= MPTS) return;
  float d = dc[m];
  #pragma unroll
  for (int c=0;c<NC;++c){
    ydc[((size_t)m*NC + c)*2    ] = kr[(size_t)c*MPTS + m]*d;
    ydc[((size_t)m*NC + c)*2 + 1] = ki[(size_t)c*MPTS + m]*d;
  }
  const float PI2 = 6.28318530717958647692f;
  float tmx = ktraj[m]        * ((float)GX/PI2);
  float tmy = ktraj[MPTS + m] * ((float)GY/PI2);
  float bx = floorf(tmx - 3.0f), by = floorf(tmy - 3.0f);
  float wx[6], wy[6];
  #pragma unroll
  for (int j=0;j<6;++j){
    wx[j] = kb_w(tmx - (bx + (float)(j+1)));
    wy[j] = kb_w(tmy - (by + (float)(j+1)));
  }
  float4* wt = (float4*)(wtab + (size_t)m*12);
  wt[0] = make_float4(wx[0], wx[1], wx[2], wx[3]);
  wt[1] = make_float4(wx[4], wx[5], wy[0], wy[1]);
  wt[2] = make_float4(wy[2], wy[3], wy[4], wy[5]);
  int ix0 = ((int)bx + 1) % GX; if (ix0 < 0) ix0 += GX;
  int iy0 = ((int)by + 1) % GY; if (iy0 < 0) iy0 += GY;
  itab[m] = make_int2(ix0, iy0);
  int tx0 = ix0 >> 5, tx1 = ((ix0 + 5) % GX) >> 5;
  int ty0 = iy0 >> 5, ty1 = ((iy0 + 5) % GY) >> 5;
  atomicAdd(&bhist[tx0*NTY+ty0],1);
  if (tx1!=tx0) atomicAdd(&bhist[tx1*NTY+ty0],1);
  if (ty1!=ty0){
    atomicAdd(&bhist[tx0*NTY+ty1],1);
    if (tx1!=tx0) atomicAdd(&bhist[tx1*NTY+ty1],1);
  }
}

__global__ __launch_bounds__(256) void bin_scan(const int* __restrict__ bhist,
                                                int* __restrict__ bstart,
                                                int* __restrict__ bcur){
  __shared__ int ps[256];
  int t = threadIdx.x;
  int v[5]; int s = 0;
  #pragma unroll
  for (int j=0;j<5;++j){ int i = t*5+j; v[j] = (i<NTILE)?bhist[i]:0; s += v[j]; }
  ps[t] = s; __syncthreads();
  for (int off=1; off<256; off<<=1){
    int x = (t>=off) ? ps[t-off] : 0;
    __syncthreads();
    ps[t] += x;
    __syncthreads();
  }
  int run = (t==0) ? 0 : ps[t-1];
  #pragma unroll
  for (int j=0;j<5;++j){
    int i = t*5+j;
    if (i<NTILE){ bstart[i]=run; bcur[i]=run; }
    run += v[j];
  }
}

__global__ void bin_fill(const int2* __restrict__ itab, int* __restrict__ bcur,
                         int* __restrict__ bent){
  int m = blockIdx.x*256 + threadIdx.x;
  if (m >= MPTS) return;
  int2 ii = itab[m];
  int tx0 = ii.x >> 5, tx1 = ((ii.x + 5) % GX) >> 5;
  int ty0 = ii.y >> 5, ty1 = ((ii.y + 5) % GY) >> 5;
  int p = atomicAdd(&bcur[tx0*NTY+ty0],1); bent[p] = m;
  if (tx1!=tx0){ p = atomicAdd(&bcur[tx1*NTY+ty0],1); bent[p] = m; }
  if (ty1!=ty0){
    p = atomicAdd(&bcur[tx0*NTY+ty1],1); bent[p] = m;
    if (tx1!=tx0){ p = atomicAdd(&bcur[tx1*NTY+ty1],1); bent[p] = m; }
  }
}

// ---------- tile gather (table-driven): thread owns 4 cells, all BC coils ----------
template<int BC>
__global__ __launch_bounds__(256) void tile_gather(const float* __restrict__ ydc,
                                                   const float* __restrict__ wtab,
                                                   const int2* __restrict__ itab,
                                                   const int* __restrict__ bstart,
                                                   const int* __restrict__ bend,
                                                   const int* __restrict__ bent,
                                                   bf16* __restrict__ A1, int c0){
  int tile = blockIdx.x;
  int tx = tile / NTY, ty = tile - tx*NTY;
  int x0 = tx*32, y0 = ty*32;
  int t = threadIdx.x;
  int kxl = t >> 3;
  int ky0l = (t & 7) * 4;
  int kxi  = x0 + kxl;
  int kyi0 = y0 + ky0l;

  __shared__ float swx[CHUNK][6], swy[CHUNK][6];
  __shared__ float sy[CHUNK][2*BC];
  __shared__ int   six0[CHUNK], siy0[CHUNK];

  float accr[4][BC], acci[4][BC];
  #pragma unroll
  for (int q=0;q<4;++q)
    #pragma unroll
    for (int c=0;c<BC;++c){ accr[q][c]=0.f; acci[q][c]=0.f; }

  int beg = bstart[tile], end = bend[tile];
  for (int s0 = beg; s0 < end; s0 += CHUNK){
    int ns = end - s0; if (ns > CHUNK) ns = CHUNK;
    __syncthreads();
    for (int i=t; i<ns; i+=256){
      int m = bent[s0+i];
      const float4* wt = (const float4*)(wtab + (size_t)m*12);
      float4 w0 = wt[0], w1 = wt[1], w2 = wt[2];
      swx[i][0]=w0.x; swx[i][1]=w0.y; swx[i][2]=w0.z; swx[i][3]=w0.w;
      swx[i][4]=w1.x; swx[i][5]=w1.y;
      swy[i][0]=w1.z; swy[i][1]=w1.w; swy[i][2]=w2.x; swy[i][3]=w2.y;
      swy[i][4]=w2.z; swy[i][5]=w2.w;
      int2 ii = itab[m];
      six0[i] = ii.x; siy0[i] = ii.y;
    }
    for (int i=t; i<ns*2*BC; i+=256){
      int s = i / (2*BC), f = i - s*(2*BC);
      sy[s][f] = ydc[((size_t)bent[s0+s]*NC + c0)*2 + f];
    }
    __syncthreads();
    for (int s=0; s<ns; ++s){
      int lx = kxi - six0[s]; if (lx < 0) lx += GX;
      if (lx < 6){
        float wx = swx[s][lx];
        int lyb = kyi0 - siy0[s]; if (lyb < 0) lyb += GY;
        float wq[4];
        #pragma unroll
        for (int q=0;q<4;++q){
          int ly = lyb + q; if (ly >= GY) ly -= GY;
          wq[q] = (ly < 6) ? wx * swy[s][ly] : 0.0f;
        }
        #pragma unroll
        for (int c=0;c<BC;++c){
          float yrc = sy[s][2*c], yic = sy[s][2*c+1];
          #pragma unroll
          for (int q=0;q<4;++q){
            accr[q][c] = fmaf(wq[q], yrc, accr[q][c]);
            acci[q][c] = fmaf(wq[q], yic, acci[q][c]);
          }
        }
      }
    }
  }

  float maskq[4];
  #pragma unroll
  for (int q=0;q<4;++q) maskq[q] = ((kyi0 + q) < GY) ? 1.0f : 0.0f;

  #pragma unroll
  for (int c=0;c<BC;++c){
    bf16x4 vr, vi;
    #pragma unroll
    for (int q=0;q<4;++q){
      vr[q] = (bf16)(accr[q][c]*maskq[q]);
      vi[q] = (bf16)(acci[q][c]*maskq[q]);
    }
    size_t base = ((size_t)((c*GX + kxi)*2)) * K1;
    *(bf16x4*)(A1 + base + kyi0)      = vr;
    *(bf16x4*)(A1 + base + K1 + kyi0) = vi;
  }
}

// ---------- twiddle gen: B1 [M1][K1], W2 [M2][K2] ----------
#define B1_ELEMS (M1*K1)
#define W2_ELEMS (M2*K2)
__global__ void gen_tw(bf16* __restrict__ B1, bf16* __restrict__ W2){
  int i = blockIdx.x*256 + threadIdx.x;
  if (i < B1_ELEMS){
    int nr = i / K1, k = i - nr*K1;
    int n = nr >> 1, p = nr & 1;
    float v = 0.f;
    if (n <= 160 && k < GY){
      int rem = (k * n) % GY;
      float ang = 6.28318530717958647692f * (float)rem / (float)GY;
      float s, c; sincosf(ang, &s, &c);
      v = p ? s : c;
    }
    B1[i] = (bf16)v;
  } else if (i < B1_ELEMS + W2_ELEMS){
    int j = i - B1_ELEMS;
    int mr = j / K2, kx = j - mr*K2;
    int r = mr >> 1, b = mr & 1;
    float v = 0.f;
    if (r < CROPN){
      int nx = (r < 160) ? (1120 + r) : (r - 160);
      int rem = (kx * nx) % GX;
      float ang = 6.28318530717958647692f * (float)rem / (float)GX;
      float s, c; sincosf(ang, &s, &c);
      v = b ? s : c;
    }
    W2[j] = (bf16)v;
  }
}

// ---------- GEMM1 persistent-M: C1t[M1=384][ncols] = B1 x A1^T, A1 read once ----------
// block: 512 threads (8 waves), 128 cols; wave w owns M rows [w*48, w*48+48)
#define LDT 40
__global__ __launch_bounds__(512, 2) void gemm1_tall(const bf16* __restrict__ A1,
                                                     const bf16* __restrict__ B1,
                                                     bf16* __restrict__ C,
                                                     int ncols){
  __shared__ bf16 As[128*LDT];   // A1 tile (cols side)
  __shared__ bf16 Bs[M1*LDT];    // B1 tile (rows side)
  int t = threadIdx.x;
  int lane = t & 63;
  int wave = t >> 6;              // 0..7
  int wm = wave * 48;
  size_t col0 = (size_t)blockIdx.x * 128;

  f32x4 zero = {0.f,0.f,0.f,0.f};
  f32x4 acc[3][8];
  #pragma unroll
  for (int m=0;m<3;++m)
    #pragma unroll
    for (int n=0;n<8;++n) acc[m][n] = zero;

  int r0 = t >> 2;                // 0..127
  int kc = (t & 3) * 8;           // 0,8,16,24
  const bf16* Ab = A1 + (col0 + r0) * K1 + kc;
  const bf16* Bb = B1 + (size_t)r0 * K1 + kc;

  bf16x8 pa  = *(const bf16x8*)(Ab);
  bf16x8 pb0 = *(const bf16x8*)(Bb);
  bf16x8 pb1 = *(const bf16x8*)(Bb + 128*K1);
  bf16x8 pb2 = *(const bf16x8*)(Bb + 256*K1);

  int lr = lane & 15, lk = (lane >> 4) * 8;

  for (int kt = 0; kt < K1; kt += 32){
    __syncthreads();
    *(bf16x8*)(As + r0*LDT + kc)       = pa;
    *(bf16x8*)(Bs + r0*LDT + kc)       = pb0;
    *(bf16x8*)(Bs + (r0+128)*LDT + kc) = pb1;
    *(bf16x8*)(Bs + (r0+256)*LDT + kc) = pb2;
    __syncthreads();

    if (kt + 32 < K1){
      pa  = *(const bf16x8*)(Ab + kt + 32);
      pb0 = *(const bf16x8*)(Bb + kt + 32);
      pb1 = *(const bf16x8*)(Bb + 128*K1 + kt + 32);
      pb2 = *(const bf16x8*)(Bb + 256*K1 + kt + 32);
    }

    bf16x8 af[3], bg[8];
    #pragma unroll
    for (int m=0;m<3;++m)
      af[m] = *(const bf16x8*)(Bs + (wm + m*16 + lr)*LDT + lk);
    #pragma unroll
    for (int n=0;n<8;++n)
      bg[n] = *(const bf16x8*)(As + (n*16 + lr)*LDT + lk);
    #pragma unroll
    for (int m=0;m<3;++m)
      #pragma unroll
      for (int n=0;n<8;++n)
        acc[m][n] = __builtin_amdgcn_mfma_f32_16x16x32_bf16(af[m], bg[n], acc[m][n], 0, 0, 0);
  }

  int lrow = (lane >> 4) * 4;
  #pragma unroll
  for (int m=0;m<3;++m)
    #pragma unroll
    for (int n=0;n<8;++n){
      size_t row = wm + m*16 + lrow;
      size_t col = col0 + n*16 + lr;
      #pragma unroll
      for (int r=0;r<4;++r)
        C[(row + r)*(size_t)ncols + col] = (bf16)acc[m][n][r];
    }
}

// ---------- pack C1t(bf16) -> A2 [nb*640][K2=1280], non-redundant ----------
__global__ void pack_A2t(const bf16* __restrict__ C1t, bf16* __restrict__ A2,
                         int nb, int ldc1){
  int i = blockIdx.x*256 + threadIdx.x;
  if (i >= nb*161*160) return;
  int kxg = i % 160;
  int rem = i / 160;
  int n   = rem % 161;
  int cl  = rem / 161;
  int kx0 = kxg*8;
  int cb  = (cl*GX + kx0)*2;
  const bf16x8* pr = (const bf16x8*)(C1t + (size_t)(2*n)*ldc1 + cb);
  const bf16x8* ps = (const bf16x8*)(C1t + (size_t)(2*n+1)*ldc1 + cb);
  float CR[8], CI[8], SR[8], SI[8];
  #pragma unroll
  for (int h=0;h<2;++h){
    bf16x8 c8 = pr[h], s8 = ps[h];
    #pragma unroll
    for (int j=0;j<4;++j){
      CR[h*4+j] = (float)c8[2*j]; CI[h*4+j] = (float)c8[2*j+1];
      SR[h*4+j] = (float)s8[2*j]; SI[h*4+j] = (float)s8[2*j+1];
    }
  }
  if (n <= 159){                       // q+ = 160+n
    bf16x8 t0, t1;
    #pragma unroll
    for (int j=0;j<8;++j){
      t0[j] = (bf16)(CR[j] - SI[j]);   // tre
      t1[j] = (bf16)(SR[j] + CI[j]);   // tim
    }
    size_t r0 = ((size_t)(cl*640 + 2*(160+n)))*K2;
    *(bf16x8*)(A2 + r0 + kx0)      = t0;
    *(bf16x8*)(A2 + r0 + K2 + kx0) = t1;
  }
  if (n >= 1){                         // q- = 160-n
    bf16x8 t0, t1;
    #pragma unroll
    for (int j=0;j<8;++j){
      t0[j] = (bf16)(CR[j] + SI[j]);   // tre
      t1[j] = (bf16)(CI[j] - SR[j]);   // tim
    }
    size_t r0 = ((size_t)(cl*640 + 2*(160-n)))*K2;
    *(bf16x8*)(A2 + r0 + kx0)      = t0;
    *(bf16x8*)(A2 + r0 + K2 + kx0) = t1;
  }
}

// ---------- bf16 GEMM, 128x128 tile, fp32 C: C[m][n] = sum_k A[m][k]*B[n][k] ----------
#define BM 128
#define BN 128
#define BK 32

__global__ __launch_bounds__(256) void gemm_bt(const bf16* __restrict__ A,
                                               const bf16* __restrict__ B,
                                               float* __restrict__ C,
                                               int K, int ldc){
  __shared__ bf16 As[BM*LDT];
  __shared__ bf16 Bs[BM*LDT];
  int t = threadIdx.x;
  int lane = t & 63;
  int wave = t >> 6;
  int wm = wave >> 1, wn = wave & 1;
  size_t tileM = (size_t)blockIdx.x * BM;
  size_t tileN = (size_t)blockIdx.y * BN;

  const bf16* Ab = A + tileM * K;
  const bf16* Bb = B + tileN * K;

  f32x4 zero = {0.f, 0.f, 0.f, 0.f};
  f32x4 acc[4][4];
  #pragma unroll
  for (int m=0;m<4;++m)
    #pragma unroll
    for (int n=0;n<4;++n) acc[m][n] = zero;

  int r0 = t >> 2;
  int kc = (t & 3) * 8;
  size_t aoff = (size_t)r0 * K + kc;

  bf16x8 a0 = *(const bf16x8*)(Ab + aoff);
  bf16x8 a1 = *(const bf16x8*)(Ab + aoff + (size_t)64*K);
  bf16x8 b0 = *(const bf16x8*)(Bb + aoff);
  bf16x8 b1 = *(const bf16x8*)(Bb + aoff + (size_t)64*K);

  int lr = lane & 15, lk = (lane >> 4) * 8;

  for (int kt = 0; kt < K; kt += BK){
    __syncthreads();
    *(bf16x8*)(As + r0*LDT + kc)      = a0;
    *(bf16x8*)(As + (r0+64)*LDT + kc) = a1;
    *(bf16x8*)(Bs + r0*LDT + kc)      = b0;
    *(bf16x8*)(Bs + (r0+64)*LDT + kc) = b1;
    __syncthreads();

    bool more = (kt + BK) < K;
    if (more){
      size_t o = aoff + kt + BK;
      a0 = *(const bf16x8*)(Ab + o);
      a1 = *(const bf16x8*)(Ab + o + (size_t)64*K);
      b0 = *(const bf16x8*)(Bb + o);
      b1 = *(const bf16x8*)(Bb + o + (size_t)64*K);
    }

    bf16x8 af[4], bg[4];
    #pragma unroll
    for (int m=0;m<4;++m)
      af[m] = *(const bf16x8*)(As + (wm*64 + m*16 + lr)*LDT + lk);
    #pragma unroll
    for (int n=0;n<4;++n)
      bg[n] = *(const bf16x8*)(Bs + (wn*64 + n*16 + lr)*LDT + lk);
    #pragma unroll
    for (int m=0;m<4;++m)
      #pragma unroll
      for (int n=0;n<4;++n)
        acc[m][n] = __builtin_amdgcn_mfma_f32_16x16x32_bf16(af[m], bg[n], acc[m][n], 0, 0, 0);
  }

  int lrow = (lane >> 4) * 4;
  #pragma unroll
  for (int m=0;m<4;++m)
    #pragma unroll
    for (int n=0;n<4;++n){
      size_t row = tileM + wm*64 + m*16 + lrow;
      size_t col = tileN + wn*64 + n*16 + lr;
      #pragma unroll
      for (int r=0;r<4;++r)
        C[(row + r)*(size_t)ldc + col] = acc[m][n][r];
    }
}

// ---------- coil combine from O[2r+b][cl*640 + 2q+a] ----------
__global__ void combine(const float* __restrict__ O,
                        const float* __restrict__ smr, const float* __restrict__ smi,
                        float* __restrict__ accum, int c0, int bc, int ldo){
  int i = blockIdx.x*256 + threadIdx.x;
  if (i >= CROPN*CROPN) return;
  int r = i / CROPN, q = i - r*CROPN;
  const float* row0 = O + (size_t)(2*r)*ldo;
  const float* row1 = O + (size_t)(2*r+1)*ldo;
  float ar = 0.f, ai = 0.f;
  for (int cl=0; cl<bc; ++cl){
    int cb = cl*640 + 2*q;
    float o00 = row0[cb], o01 = row0[cb+1];
    float o10 = row1[cb], o11 = row1[cb+1];
    float re = o00 - o11;
    float im = o01 + o10;
    size_t sidx = ((size_t)(c0+cl)*HH + (160+r))*WW + (77+q);
    float sr = smr[sidx], si = smi[sidx];
    ar += sr*re + si*im;
    ai += sr*im - si*re;
  }
  accum[2*i] += ar; accum[2*i+1] += ai;
}

// ---------- deapodization + magnitude ----------
__device__ __forceinline__ float deapod_f(float n, float G){
  float x = 3.14159265358979323846f * 6.0f * n / G;
  float z = 197.1216f - x*x;
  float sz = sqrtf(fabsf(z) + 1e-12f);
  float K;
  if (z > 0.0f){
    float e = __expf(sz);
    K = (e - 1.0f/e)*0.5f/sz;
  } else {
    K = __sinf(sz)/sz;
  }
  return 1.0f/K;
}

__global__ void final_mag(const float* __restrict__ accum, float* __restrict__ out){
  int i = blockIdx.x*256 + threadIdx.x;
  if (i >= CROPN*CROPN) return;
  int r  = i / CROPN;
  int cc = i - r*CROPN;
  float dx = deapod_f((float)(r  - 160), (float)GX);
  float dy = deapod_f((float)(cc - 160), (float)GY);
  float re = accum[2*i], im = accum[2*i+1];
  out[i] = sqrtf(re*re + im*im) * dx * dy;
}

// tile_gather dispatch helper
static void launch_gather(int nb, const float* ydc, const float* wtab, const int2* itab,
                          const int* bstart, const int* bcur, const int* bent,
                          bf16* A1, int c0, hipStream_t stream){
  switch (nb){
    case 1:  tile_gather<1><<<NTILE,256,0,stream>>>(ydc,wtab,itab,bstart,bcur,bent,A1,c0); break;
    case 2:  tile_gather<2><<<NTILE,256,0,stream>>>(ydc,wtab,itab,bstart,bcur,bent,A1,c0); break;
    case 3:  tile_gather<3><<<NTILE,256,0,stream>>>(ydc,wtab,itab,bstart,bcur,bent,A1,c0); break;
    case 4:  tile_gather<4><<<NTILE,256,0,stream>>>(ydc,wtab,itab,bstart,bcur,bent,A1,c0); break;
    case 5:  tile_gather<5><<<NTILE,256,0,stream>>>(ydc,wtab,itab,bstart,bcur,bent,A1,c0); break;
    case 6:  tile_gather<6><<<NTILE,256,0,stream>>>(ydc,wtab,itab,bstart,bcur,bent,A1,c0); break;
    case 7:  tile_gather<7><<<NTILE,256,0,stream>>>(ydc,wtab,itab,bstart,bcur,bent,A1,c0); break;
    case 8:  tile_gather<8><<<NTILE,256,0,stream>>>(ydc,wtab,itab,bstart,bcur,bent,A1,c0); break;
    case 9:  tile_gather<9><<<NTILE,256,0,stream>>>(ydc,wtab,itab,bstart,bcur,bent,A1,c0); break;
    case 10: tile_gather<10><<<NTILE,256,0,stream>>>(ydc,wtab,itab,bstart,bcur,bent,A1,c0); break;
    case 11: tile_gather<11><<<NTILE,256,0,stream>>>(ydc,wtab,itab,bstart,bcur,bent,A1,c0); break;
    case 12: tile_gather<12><<<NTILE,256,0,stream>>>(ydc,wtab,itab,bstart,bcur,bent,A1,c0); break;
    case 13: tile_gather<13><<<NTILE,256,0,stream>>>(ydc,wtab,itab,bstart,bcur,bent,A1,c0); break;
    case 14: tile_gather<14><<<NTILE,256,0,stream>>>(ydc,wtab,itab,bstart,bcur,bent,A1,c0); break;
    default: tile_gather<15><<<NTILE,256,0,stream>>>(ydc,wtab,itab,bstart,bcur,bent,A1,c0); break;
  }
}

extern "C" void kernel_launch(void* const* d_in, const int* in_sizes, int n_in,
                              void* d_out, int out_size, void* d_ws, size_t ws_size,
                              hipStream_t stream){
  const float* kr    = (const float*)d_in[0];
  const float* ki    = (const float*)d_in[1];
  const float* ktraj = (const float*)d_in[2];
  const float* dc    = (const float*)d_in[3];
  const float* smr   = (const float*)d_in[4];
  const float* smi   = (const float*)d_in[5];
  float* out = (float*)d_out;

  // ---- workspace carve (bytes) ----
  const size_t acc_b   = (size_t)CROPN*CROPN*2*4;
  const size_t B1_b    = (size_t)M1*K1*2;            //   737,280
  const size_t W2_b    = (size_t)M2*K2*2;            // 1,638,400
  const size_t ydc_b   = (size_t)MPTS*NC*2*4;
  const size_t wtab_b  = (size_t)MPTS*12*4;
  const size_t itab_b  = (size_t)MPTS*8;
  const size_t bh_b    = 8192;
  const size_t bent_b  = (size_t)MAXENT*4;
  const size_t fixed_b = acc_b+B1_b+W2_b+ydc_b+wtab_b+itab_b+3*bh_b+bent_b;

  const size_t A1_pc   = (size_t)GX*2*K1*2;          // 4,915,200 (A2: 640*1280*2=1,638,400 aliases)
  const size_t C1_pc   = (size_t)GX*2*M1*2;          // 1,966,080 (O: 640*640*4=1,638,400 aliases)
  const size_t percoil = A1_pc + C1_pc;              // 6,881,280

  int bc = 1;
  if (ws_size > fixed_b + percoil){
    size_t b = (ws_size - fixed_b) / percoil;
    bc = (int)(b > NC ? NC : b);
    if (bc < 1) bc = 1;
  }

  char* p = (char*)d_ws;
  float* accum  = (float*)p; p += acc_b;
  bf16*  B1     = (bf16*)p;  p += B1_b;
  bf16*  W2     = (bf16*)p;  p += W2_b;
  float* ydc    = (float*)p; p += ydc_b;
  float* wtab   = (float*)p; p += wtab_b;
  int2*  itab   = (int2*)p;  p += itab_b;
  int*   bhist  = (int*)p;   p += bh_b;
  int*   bstart = (int*)p;   p += bh_b;
  int*   bcur   = (int*)p;   p += bh_b;
  int*   bent   = (int*)p;   p += bent_b;
  bf16*  A1     = (bf16*)p;
  bf16*  A2     = (bf16*)p;  p += (size_t)bc*A1_pc;   // A2 aliases A1 (dead after GEMM1)
  bf16*  C1t    = (bf16*)p;
  float* O      = (float*)p; p += (size_t)bc*C1_pc;   // O aliases C1t (dead after pack)

  // ---- one-time builds ----
  hipMemsetAsync(bhist, 0, NTILE*4, stream);
  prep<<<(MPTS+255)/256, 256, 0, stream>>>(kr, ki, dc, ktraj, ydc, wtab, itab, bhist);
  bin_scan<<<1, 256, 0, stream>>>(bhist, bstart, bcur);
  bin_fill<<<(MPTS+255)/256, 256, 0, stream>>>(itab, bcur, bent);
  gen_tw<<<(B1_ELEMS+W2_ELEMS+255)/256, 256, 0, stream>>>(B1, W2);
  hipMemsetAsync(accum, 0, acc_b, stream);

  // ---- per coil-batch pipeline (single batch when bc==15) ----
  for (int c0 = 0; c0 < NC; c0 += bc){
    int nb = NC - c0; if (nb > bc) nb = bc;
    int ncols = nb*2560;

    launch_gather(nb, ydc, wtab, itab, bstart, bcur, bent, A1, c0, stream);

    // GEMM1 persistent-M: C1t[384][ncols] = B1 x A1^T (A1 read once)
    gemm1_tall<<<ncols/128, 512, 0, stream>>>(A1, B1, C1t, ncols);

    int tot2 = nb*161*160;
    pack_A2t<<<(tot2+255)/256, 256, 0, stream>>>(C1t, A2, nb, ncols);

    // GEMM2: O[640][nb*640] = W2 x A2^T (K=1280)
    gemm_bt<<<dim3(M2/BM, nb*640/BN), 256, 0, stream>>>(W2, A2, O, K2, nb*640);

    combine<<<(CROPN*CROPN+255)/256, 256, 0, stream>>>(O, smr, smi, accum, c0, nb, nb*640);
  }
  final_mag<<<(CROPN*CROPN+255)/256, 256, 0, stream>>>(accum, out);
}